// Round 5
// baseline (998.219 us; speedup 1.0000x reference)
//
#include <hip/hip_runtime.h>
#include <math.h>

#define NPTS 32768
#define BN_RSQ 0.9999950000374997f

typedef __attribute__((ext_vector_type(8))) short short8;
typedef __attribute__((ext_vector_type(4))) float floatx4;

// Polynomial GELU (no transcendentals): gelu(x) = x * clamp01(0.5 + t*P(t^2)),
// t = clamp(x, -3, 3). Collocated at x=0.75/1.5/2.25/3; max abs err ~0.015,
// below bf16 quantization noise of downstream operands.
__device__ __forceinline__ float gelu_f(float v) {
    float t = fminf(fmaxf(v, -3.0f), 3.0f);
    float t2 = t * t;
    float p = fmaf(t2, fmaf(t2, fmaf(t2, -2.83231e-4f, 6.51008e-3f), -6.12871e-2f), 0.396958f);
    float phi = fmaf(t, p, 0.5f);
    phi = fminf(fmaxf(phi, 0.0f), 1.0f);
    return v * phi;
}
__device__ __forceinline__ unsigned short f2bf(float f) {
    unsigned u = __float_as_uint(f) + 0x8000u;
    return (unsigned short)(u >> 16);
}
// pack two floats to (bf16(hi)<<16)|bf16(lo) in 3 instrs (2 adds + v_perm)
__device__ __forceinline__ unsigned pack_bf2(float lo, float hi) {
    unsigned ul = __float_as_uint(lo) + 0x8000u;
    unsigned uh = __float_as_uint(hi) + 0x8000u;
    return __builtin_amdgcn_perm(uh, ul, 0x07060302u);
}
__device__ __forceinline__ float bf2f(unsigned u) {
    return __uint_as_float(u << 16);
}

// ---------------------------------------------------------------------------
// Folded matrices per depth: Weff[i] = w1@w2@w3a_top (3x128),
// cbias[i] = (b1@w2 + b2)@w3a_top + b3a (128)
// ---------------------------------------------------------------------------
__global__ __launch_bounds__(128) void precompute_kernel(
    const float* __restrict__ nca_w1, const float* __restrict__ nca_b1,
    const float* __restrict__ nca_w2, const float* __restrict__ nca_b2,
    const float* __restrict__ nca_w3a, const float* __restrict__ nca_b3a,
    float* __restrict__ Weff, float* __restrict__ cbias)
{
    int i = blockIdx.x;
    int t = threadIdx.x;
    const float* w1 = nca_w1 + i * 3 * 64;
    const float* b1 = nca_b1 + i * 64;
    const float* w2 = nca_w2 + i * 64 * 64;
    const float* b2 = nca_b2 + i * 64;
    const float* w3a = nca_w3a + i * 128 * 128;
    const float* b3a = nca_b3a + i * 128;

    __shared__ float u[3][64];
    __shared__ float v[64];
    if (t < 64) {
        for (int r = 0; r < 3; ++r) {
            float s = 0.f;
            for (int m = 0; m < 64; ++m) s += w1[r * 64 + m] * w2[m * 64 + t];
            u[r][t] = s;
        }
        float s = 0.f;
        for (int m = 0; m < 64; ++m) s += b1[m] * w2[m * 64 + t];
        v[t] = s + b2[t];
    }
    __syncthreads();
    for (int r = 0; r < 3; ++r) {
        float s = 0.f;
        for (int m = 0; m < 64; ++m) s += u[r][m] * w3a[m * 128 + t];
        Weff[i * 384 + r * 128 + t] = s;
    }
    {
        float s = 0.f;
        for (int m = 0; m < 64; ++m) s += v[m] * w3a[m * 128 + t];
        cbias[i * 128 + t] = s + b3a[t];
    }
}

// ---------------------------------------------------------------------------
// Generic B-fragment packer (bf16 MFMA B layout), zero-pad beyond Kr,
// optional per-column gamma fold.
// ---------------------------------------------------------------------------
__global__ __launch_bounds__(64) void pack_all(
    const float* __restrict__ bm_w1, const float* __restrict__ bm_w2,
    const float* __restrict__ m_w1, const float* __restrict__ m_w2,
    const float* __restrict__ lfa_proj, const float* __restrict__ pp_w,
    const float* __restrict__ nca_w3a, const float* __restrict__ nca_w3b,
    const float* __restrict__ ne_w3, const float* __restrict__ gpe_w,
    const float* __restrict__ ne_w1, const float* __restrict__ ne_g1,
    const float* __restrict__ ne_w2, const float* __restrict__ ne_g2,
    unsigned short* __restrict__ P_bm1, unsigned short* __restrict__ P_bm2,
    unsigned short* __restrict__ P_m1, unsigned short* __restrict__ P_m2,
    unsigned short* __restrict__ P_proj, unsigned short* __restrict__ P_pp,
    unsigned short* __restrict__ P_w3a, unsigned short* __restrict__ P_w3b,
    unsigned short* __restrict__ P_ne3, unsigned short* __restrict__ P_gpe,
    unsigned short* __restrict__ P_ne1, unsigned short* __restrict__ P_ne2)
{
    int b = blockIdx.x, l = threadIdx.x;
    const float* src; unsigned short* dst; int K, C, fb; int Kr = 0;
    const float* fold = nullptr;
    if (b < 64)       { src = bm_w1; dst = P_bm1; K = 128; C = 256; fb = b; }
    else if (b < 128) { src = bm_w2; dst = P_bm2; K = 256; C = 128; fb = b - 64; }
    else if (b < 256) { int i = (b - 128) >> 6; src = m_w1 + i * 32768; dst = P_m1 + i * 32768; K = 128; C = 256; fb = (b - 128) & 63; }
    else if (b < 384) { int i = (b - 256) >> 6; src = m_w2 + i * 32768; dst = P_m2 + i * 32768; K = 256; C = 128; fb = (b - 256) & 63; }
    else if (b < 512) { int i = (b - 384) >> 5; src = lfa_proj + i * 16384; dst = P_proj + i * 16384; K = 128; C = 128; fb = (b - 384) & 31; }
    else if (b < 576) { src = pp_w; dst = P_pp; K = 128; C = 256; fb = b - 512; }
    else if (b < 640) { int i = (b - 576) >> 4; src = nca_w3a + i * 16384 + 64 * 128; dst = P_w3a + i * 8192; K = 64; C = 128; fb = (b - 576) & 15; }
    else if (b < 768) { int i = (b - 640) >> 5; src = nca_w3b + i * 16384; dst = P_w3b + i * 16384; K = 128; C = 128; fb = (b - 640) & 31; }
    else if (b < 776) { src = ne_w3; dst = P_ne3; K = 32; C = 128; fb = b - 768; }
    else if (b < 792) { src = gpe_w; dst = P_gpe; K = 64; C = 128; fb = b - 776; }
    else if (b == 792){ src = ne_w1; dst = P_ne1; K = 32; C = 16; fb = 0; Kr = 10; fold = ne_g1; }
    else              { src = ne_w2; dst = P_ne2; K = 32; C = 32; fb = b - 793; Kr = 16; fold = ne_g2; }
    if (Kr == 0) Kr = K;
    int Kc = K >> 5;
    int tile = fb / Kc, chunk = fb % Kc;
    unsigned short* o = dst + ((size_t)fb * 64 + l) * 8;
    #pragma unroll
    for (int j = 0; j < 8; ++j) {
        int kk = chunk * 32 + (l >> 4) * 8 + j;
        int nn = tile * 16 + (l & 15);
        float v = 0.f;
        if (kk < Kr) {
            v = src[kk * C + nn];
            if (fold) v *= fold[nn] * BN_RSQ;
        }
        o[j] = f2bf(v);
    }
}

// ---------------------------------------------------------------------------
// Neighbor embedding: 4 independent waves/block, zero barriers, all 3 layers
// MFMA. grid 1024 x 256, 8 points/wave.
// ---------------------------------------------------------------------------
__global__ __launch_bounds__(256) void nbr_embed_v2(
    const float* __restrict__ x, const float* __restrict__ xyz,
    const int* __restrict__ knn,
    const float* __restrict__ ne_b1, const float* __restrict__ ne_b2,
    const unsigned short* __restrict__ P_ne1, const unsigned short* __restrict__ P_ne2,
    const unsigned short* __restrict__ P_ne3,
    const float* __restrict__ nbr_g, const float* __restrict__ nbr_b,
    float* __restrict__ dxyz_out, float* __restrict__ feat)
{
    int t = threadIdx.x, w = t >> 6, l = t & 63, q = l >> 4, r16 = l & 15;
    __shared__ __align__(16) unsigned short h1L[4][16][24];
    __shared__ __align__(16) unsigned short h2L[4][16][40];

    short8 B1 = ((const short8*)P_ne1)[l];
    short8 B2[2], B3[8];
    B2[0] = ((const short8*)P_ne2)[l];
    B2[1] = ((const short8*)P_ne2)[64 + l];
    #pragma unroll
    for (int tt = 0; tt < 8; ++tt) B3[tt] = ((const short8*)P_ne3)[tt * 64 + l];
    float b1r = ne_b1[r16];
    float b2r0 = ne_b2[r16], b2r1 = ne_b2[16 + r16];
    float bg0 = nbr_g[l] * BN_RSQ, bb0 = nbr_b[l];
    float bg1 = nbr_g[l + 64] * BN_RSQ, bb1 = nbr_b[l + 64];
    int nbase = blockIdx.x * 32 + w * 8;
    floatx4 z4 = {0.f, 0.f, 0.f, 0.f};

    for (int pp = 0; pp < 8; ++pp) {
        int n = nbase + pp;
        int id = knn[n * 16 + r16];
        float f0 = 0.f, f1 = 0.f, f2 = 0.f, f3 = 0.f, f4 = 0.f, f5 = 0.f, f6 = 0.f, f7 = 0.f;
        if (q == 0) {
            f0 = xyz[(size_t)id * 3 + 0] - xyz[(size_t)n * 3 + 0];
            f1 = xyz[(size_t)id * 3 + 1] - xyz[(size_t)n * 3 + 1];
            f2 = xyz[(size_t)id * 3 + 2] - xyz[(size_t)n * 3 + 2];
            dxyz_out[(size_t)n * 48 + r16 * 3 + 0] = f0;
            dxyz_out[(size_t)n * 48 + r16 * 3 + 1] = f1;
            dxyz_out[(size_t)n * 48 + r16 * 3 + 2] = f2;
            f3 = x[(size_t)id * 7 + 0]; f4 = x[(size_t)id * 7 + 1];
            f5 = x[(size_t)id * 7 + 2]; f6 = x[(size_t)id * 7 + 3];
            f7 = x[(size_t)id * 7 + 4];
        } else if (q == 1) {
            f0 = x[(size_t)id * 7 + 5]; f1 = x[(size_t)id * 7 + 6];
        }
        uint4 au = make_uint4(pack_bf2(f0, f1), pack_bf2(f2, f3),
                              pack_bf2(f4, f5), pack_bf2(f6, f7));
        short8 a1 = __builtin_bit_cast(short8, au);
        floatx4 c1 = __builtin_amdgcn_mfma_f32_16x16x32_bf16(a1, B1, z4, 0, 0, 0);
        #pragma unroll
        for (int rg = 0; rg < 4; ++rg)
            h1L[w][q * 4 + rg][r16] = f2bf(gelu_f(c1[rg] + b1r));

        short8 a2 = {0, 0, 0, 0, 0, 0, 0, 0};
        if (q < 2) a2 = *(const short8*)&h1L[w][r16][q * 8];
        #pragma unroll
        for (int nt = 0; nt < 2; ++nt) {
            floatx4 c2 = __builtin_amdgcn_mfma_f32_16x16x32_bf16(a2, B2[nt], z4, 0, 0, 0);
            float br = nt ? b2r1 : b2r0;
            #pragma unroll
            for (int rg = 0; rg < 4; ++rg)
                h2L[w][q * 4 + rg][nt * 16 + r16] = f2bf(gelu_f(c2[rg] + br));
        }

        short8 a3 = *(const short8*)&h2L[w][r16][q * 8];
        float keep0 = 0.f, keep1 = 0.f;
        #pragma unroll
        for (int tt = 0; tt < 8; ++tt) {
            floatx4 c3 = __builtin_amdgcn_mfma_f32_16x16x32_bf16(a3, B3[tt], z4, 0, 0, 0);
            float mx = fmaxf(fmaxf(c3.x, c3.y), fmaxf(c3.z, c3.w));
            mx = fmaxf(mx, __shfl_xor(mx, 16));
            mx = fmaxf(mx, __shfl_xor(mx, 32));
            if (tt == q)     keep0 = mx;
            if (tt == q + 4) keep1 = mx;
        }
        feat[(size_t)n * 128 + l]      = keep0 * bg0 + bb0;
        feat[(size_t)n * 128 + l + 64] = keep1 * bg1 + bb1;
    }
}

// ---------------------------------------------------------------------------
// Residual MLP via MFMA, optional fused gpe pre-pass and xp-projection tail.
// ---------------------------------------------------------------------------
__global__ __launch_bounds__(256, 2) void mlp_mfma(
    float* __restrict__ feat,
    const unsigned short* __restrict__ P1, const float* __restrict__ b1,
    const unsigned short* __restrict__ P2,
    const float* __restrict__ g, const float* __restrict__ b,
    const unsigned short* __restrict__ P_gpe, const float* __restrict__ g_pos,
    const unsigned short* __restrict__ P_proj, unsigned short* __restrict__ xpb)
{
    int t = threadIdx.x, w = t >> 6, l = t & 63;
    int q = l >> 4, r16 = l & 15;
    __shared__ __align__(16) unsigned short aS[16][136];
    __shared__ __align__(16) unsigned short hS[16][264];
    __shared__ __align__(16) float fS[16][132];

    const short8* B1 = (const short8*)P1;
    const short8* B2 = (const short8*)P2;
    short8 b1f[4][4];
    #pragma unroll
    for (int nt = 0; nt < 4; ++nt)
        #pragma unroll
        for (int ch = 0; ch < 4; ++ch)
            b1f[nt][ch] = B1[((w * 4 + nt) * 4 + ch) * 64 + l];
    short8 b2f[2][8];
    #pragma unroll
    for (int nt = 0; nt < 2; ++nt)
        #pragma unroll
        for (int ch = 0; ch < 8; ++ch)
            b2f[nt][ch] = B2[((w * 2 + nt) * 8 + ch) * 64 + l];
    float bb1[4];
    #pragma unroll
    for (int nt = 0; nt < 4; ++nt) bb1[nt] = b1[w * 64 + nt * 16 + r16];
    float gg[2], bb[2];
    #pragma unroll
    for (int nt = 0; nt < 2; ++nt) {
        int c = w * 32 + nt * 16 + r16;
        gg[nt] = g[c] * BN_RSQ; bb[nt] = b[c];
    }
    floatx4 z4 = {0.f, 0.f, 0.f, 0.f};

    for (int itc = 0; itc < 4; ++itc) {
        int n0 = blockIdx.x * 64 + itc * 16;
        {
            int row = t >> 4, c8 = (t & 15) * 8;
            float4 fa = *(const float4*)&feat[(size_t)(n0 + row) * 128 + c8];
            float4 fb4 = *(const float4*)&feat[(size_t)(n0 + row) * 128 + c8 + 4];
            *(float4*)&fS[row][c8] = fa;
            *(float4*)&fS[row][c8 + 4] = fb4;
            if (!P_gpe) {
                *(uint4*)&aS[row][c8] = make_uint4(
                    pack_bf2(fa.x, fa.y), pack_bf2(fa.z, fa.w),
                    pack_bf2(fb4.x, fb4.y), pack_bf2(fb4.z, fb4.w));
            }
        }
        __syncthreads();

        if (P_gpe) {
            const short8* Bg = (const short8*)P_gpe;
            floatx4 cg[2] = {z4, z4};
            #pragma unroll
            for (int ch = 0; ch < 2; ++ch) {
                const float* gp = &g_pos[(size_t)(n0 + r16) * 64 + ch * 32 + q * 8];
                float4 ga = *(const float4*)gp;
                float4 gb4 = *(const float4*)(gp + 4);
                uint4 au = make_uint4(pack_bf2(ga.x, ga.y), pack_bf2(ga.z, ga.w),
                                      pack_bf2(gb4.x, gb4.y), pack_bf2(gb4.z, gb4.w));
                short8 ag = __builtin_bit_cast(short8, au);
                #pragma unroll
                for (int nt = 0; nt < 2; ++nt)
                    cg[nt] = __builtin_amdgcn_mfma_f32_16x16x32_bf16(ag, Bg[((2 * w + nt) * 2 + ch) * 64 + l], cg[nt], 0, 0, 0);
            }
            #pragma unroll
            for (int nt = 0; nt < 2; ++nt) {
                int c = (2 * w + nt) * 16 + r16;
                #pragma unroll
                for (int rg = 0; rg < 4; ++rg) {
                    int row = q * 4 + rg;
                    float v = fS[row][c] + cg[nt][rg];
                    fS[row][c] = v;
                    aS[row][c] = f2bf(v);
                }
            }
            __syncthreads();
        }

        floatx4 acc1[4];
        #pragma unroll
        for (int nt = 0; nt < 4; ++nt) acc1[nt] = z4;
        #pragma unroll
        for (int ch = 0; ch < 4; ++ch) {
            short8 af = *(const short8*)&aS[r16][ch * 32 + q * 8];
            #pragma unroll
            for (int nt = 0; nt < 4; ++nt)
                acc1[nt] = __builtin_amdgcn_mfma_f32_16x16x32_bf16(af, b1f[nt][ch], acc1[nt], 0, 0, 0);
        }
        #pragma unroll
        for (int nt = 0; nt < 4; ++nt) {
            int c = w * 64 + nt * 16 + r16;
            #pragma unroll
            for (int rg = 0; rg < 4; ++rg)
                hS[q * 4 + rg][c] = f2bf(gelu_f(acc1[nt][rg] + bb1[nt]));
        }
        __syncthreads();

        floatx4 acc2[2];
        #pragma unroll
        for (int nt = 0; nt < 2; ++nt) acc2[nt] = z4;
        #pragma unroll
        for (int ch = 0; ch < 8; ++ch) {
            short8 af = *(const short8*)&hS[r16][ch * 32 + q * 8];
            #pragma unroll
            for (int nt = 0; nt < 2; ++nt)
                acc2[nt] = __builtin_amdgcn_mfma_f32_16x16x32_bf16(af, b2f[nt][ch], acc2[nt], 0, 0, 0);
        }
        #pragma unroll
        for (int nt = 0; nt < 2; ++nt) {
            int c = w * 32 + nt * 16 + r16;
            #pragma unroll
            for (int rg = 0; rg < 4; ++rg) {
                int row = q * 4 + rg;
                float v = fS[row][c] + acc2[nt][rg] * gg[nt] + bb[nt];
                feat[(size_t)(n0 + row) * 128 + c] = v;
                if (P_proj) aS[row][c] = f2bf(v);
            }
        }
        if (P_proj) {
            __syncthreads();
            const short8* Bp = (const short8*)P_proj;
            #pragma unroll
            for (int nt = 0; nt < 2; ++nt) {
                int tg = w * 2 + nt;
                floatx4 ap = z4;
                #pragma unroll
                for (int ch = 0; ch < 4; ++ch) {
                    short8 af = *(const short8*)&aS[r16][ch * 32 + q * 8];
                    ap = __builtin_amdgcn_mfma_f32_16x16x32_bf16(af, Bp[(tg * 4 + ch) * 64 + l], ap, 0, 0, 0);
                }
                #pragma unroll
                for (int rg = 0; rg < 4; ++rg)
                    xpb[(size_t)(n0 + q * 4 + rg) * 128 + tg * 16 + r16] = f2bf(ap[rg]);
            }
        }
        __syncthreads();
    }
}

// ---------------------------------------------------------------------------
// xp = feat @ proj (128->128), bf16 output (depths 1,3).
// ---------------------------------------------------------------------------
__global__ __launch_bounds__(256) void linear_mfma(
    const float* __restrict__ feat, const unsigned short* __restrict__ P,
    unsigned short* __restrict__ xp)
{
    int t = threadIdx.x, w = t >> 6, l = t & 63;
    int q = l >> 4, r16 = l & 15;
    __shared__ __align__(16) unsigned short aS[16][136];
    const short8* B = (const short8*)P;
    short8 bf[2][4];
    #pragma unroll
    for (int nt = 0; nt < 2; ++nt)
        #pragma unroll
        for (int ch = 0; ch < 4; ++ch)
            bf[nt][ch] = B[((w * 2 + nt) * 4 + ch) * 64 + l];
    floatx4 z4 = {0.f, 0.f, 0.f, 0.f};

    for (int itc = 0; itc < 4; ++itc) {
        int n0 = blockIdx.x * 64 + itc * 16;
        {
            int row = t >> 4, c8 = (t & 15) * 8;
            float4 fa = *(const float4*)&feat[(size_t)(n0 + row) * 128 + c8];
            float4 fb4 = *(const float4*)&feat[(size_t)(n0 + row) * 128 + c8 + 4];
            *(uint4*)&aS[row][c8] = make_uint4(
                pack_bf2(fa.x, fa.y), pack_bf2(fa.z, fa.w),
                pack_bf2(fb4.x, fb4.y), pack_bf2(fb4.z, fb4.w));
        }
        __syncthreads();
        floatx4 acc[2];
        #pragma unroll
        for (int nt = 0; nt < 2; ++nt) acc[nt] = z4;
        #pragma unroll
        for (int ch = 0; ch < 4; ++ch) {
            short8 af = *(const short8*)&aS[r16][ch * 32 + q * 8];
            #pragma unroll
            for (int nt = 0; nt < 2; ++nt)
                acc[nt] = __builtin_amdgcn_mfma_f32_16x16x32_bf16(af, bf[nt][ch], acc[nt], 0, 0, 0);
        }
        #pragma unroll
        for (int nt = 0; nt < 2; ++nt) {
            int c = w * 32 + nt * 16 + r16;
            #pragma unroll
            for (int rg = 0; rg < 4; ++rg)
                xp[(size_t)(n0 + q * 4 + rg) * 128 + c] = f2bf(acc[nt][rg]);
        }
        __syncthreads();
    }
}

// ---------------------------------------------------------------------------
// Postproj: out = BN(feat) @ pp_w (128->256), fp32 out.
// ---------------------------------------------------------------------------
__global__ __launch_bounds__(256) void postproj_mfma(
    float* __restrict__ out, const float* __restrict__ feat,
    const float* __restrict__ g, const float* __restrict__ b,
    const unsigned short* __restrict__ P)
{
    int t = threadIdx.x, w = t >> 6, l = t & 63;
    int q = l >> 4, r16 = l & 15;
    __shared__ __align__(16) unsigned short aS[16][136];
    const short8* B = (const short8*)P;
    short8 bf[4][4];
    #pragma unroll
    for (int nt = 0; nt < 4; ++nt)
        #pragma unroll
        for (int ch = 0; ch < 4; ++ch)
            bf[nt][ch] = B[((w * 4 + nt) * 4 + ch) * 64 + l];
    floatx4 z4 = {0.f, 0.f, 0.f, 0.f};

    for (int itc = 0; itc < 4; ++itc) {
        int n0 = blockIdx.x * 64 + itc * 16;
        {
            int row = t >> 4, c8 = (t & 15) * 8;
            const float* fp = &feat[(size_t)(n0 + row) * 128 + c8];
            float4 fa = *(const float4*)fp;
            float4 fb4 = *(const float4*)(fp + 4);
            float4 ga = *(const float4*)&g[c8], gb4 = *(const float4*)&g[c8 + 4];
            float4 ba = *(const float4*)&b[c8], bb4 = *(const float4*)&b[c8 + 4];
            *(uint4*)&aS[row][c8] = make_uint4(
                pack_bf2(fa.x * ga.x * BN_RSQ + ba.x, fa.y * ga.y * BN_RSQ + ba.y),
                pack_bf2(fa.z * ga.z * BN_RSQ + ba.z, fa.w * ga.w * BN_RSQ + ba.w),
                pack_bf2(fb4.x * gb4.x * BN_RSQ + bb4.x, fb4.y * gb4.y * BN_RSQ + bb4.y),
                pack_bf2(fb4.z * gb4.z * BN_RSQ + bb4.z, fb4.w * gb4.w * BN_RSQ + bb4.w));
        }
        __syncthreads();
        floatx4 acc[4];
        #pragma unroll
        for (int nt = 0; nt < 4; ++nt) acc[nt] = z4;
        #pragma unroll
        for (int ch = 0; ch < 4; ++ch) {
            short8 af = *(const short8*)&aS[r16][ch * 32 + q * 8];
            #pragma unroll
            for (int nt = 0; nt < 4; ++nt)
                acc[nt] = __builtin_amdgcn_mfma_f32_16x16x32_bf16(af, bf[nt][ch], acc[nt], 0, 0, 0);
        }
        #pragma unroll
        for (int nt = 0; nt < 4; ++nt) {
            int c = w * 64 + nt * 16 + r16;
            #pragma unroll
            for (int rg = 0; rg < 4; ++rg)
                out[(size_t)(n0 + q * 4 + rg) * 256 + c] = acc[nt][rg];
        }
        __syncthreads();
    }
}

// ---------------------------------------------------------------------------
// LFA v5: 8 points/wave, grid 1024, 4 blocks/CU (36.1 KB LDS), poly GELU,
// perm-packed bf16, p_local buffer unioned into gS.
// ---------------------------------------------------------------------------
__global__ __launch_bounds__(256, 4) void lfa_mfma4(
    float* __restrict__ feat, const unsigned short* __restrict__ xpb,
    const float* __restrict__ dxyz, const int* __restrict__ knn,
    const float* __restrict__ w1, const float* __restrict__ b1,
    const unsigned short* __restrict__ P_w3a, const float* __restrict__ Weff,
    const float* __restrict__ cbias, const unsigned short* __restrict__ P_w3b,
    const float* __restrict__ b3b,
    const float* __restrict__ lg, const float* __restrict__ lb)
{
    int w = threadIdx.x >> 6, l = threadIdx.x & 63;
    int q = l >> 4, r16 = l & 15;

    __shared__ __align__(16) float dxS[4][8][64];
    __shared__ __align__(16) unsigned short tvS[4][8][132];
    // gS doubles as: phase A = p_local rows (points 0..7, cols 0..63);
    // phase B = GELU(a) rows (neighbors 0..15, cols 0..127). Same-wave
    // sequential use, no cross-wave sharing.
    __shared__ __align__(16) unsigned short gS[4][16][136];
    __shared__ int idS[4][128];

    int nbase = blockIdx.x * 32 + w * 8;

    #pragma unroll
    for (int i = 0; i < 2; ++i)
        idS[w][i * 64 + l] = knn[(size_t)nbase * 16 + i * 64 + l];
    #pragma unroll
    for (int i = 0; i < 6; ++i) {
        int gI = i * 64 + l;                 // 0..383
        int p = gI / 48, rr = gI % 48;
        int k = rr / 3, d = rr - k * 3;
        dxS[w][p][k * 4 + d] = dxyz[(size_t)nbase * 48 + gI];
    }

    short8 bfr[8][4];
    {
        const short8* bp = (const short8*)P_w3b;
        #pragma unroll
        for (int tt = 0; tt < 8; ++tt)
            #pragma unroll
            for (int ch = 0; ch < 4; ++ch)
                bfr[tt][ch] = bp[(tt * 4 + ch) * 64 + l];
    }
    int c0 = 2 * l;
    float2 we0 = *(const float2*)&Weff[c0];
    float2 we1 = *(const float2*)&Weff[128 + c0];
    float2 we2 = *(const float2*)&Weff[256 + c0];
    float w1r0 = w1[l], w1r1 = w1[64 + l], w1r2 = w1[128 + l], b1l = b1[l];
    float b3b0 = b3b[l], b3b1 = b3b[l + 64];
    float lg0 = lg[l] * BN_RSQ, lg1 = lg[l + 64] * BN_RSQ;
    float lb0 = lb[l], lb1 = lb[l + 64];
    floatx4 z4 = {0.f, 0.f, 0.f, 0.f};

    // phase A: p_local for 8 points into gS rows 0..7 (lane l owns hidden dim l)
    for (int p = 0; p < 8; ++p) {
        float m = -1e30f;
        #pragma unroll
        for (int k = 0; k < 16; ++k) {
            float4 d4 = *(const float4*)&dxS[w][p][k * 4];
            m = fmaxf(m, b1l + d4.x * w1r0 + d4.y * w1r1 + d4.z * w1r2);
        }
        gS[w][p][l] = f2bf(m);
    }

    // tv = cbias + pl @ w3a_bot : rows 8-15 garbage, discarded via q<2
    {
        floatx4 tacc[8];
        #pragma unroll
        for (int tt = 0; tt < 8; ++tt) tacc[tt] = z4;
        const short8* bpA = (const short8*)P_w3a;
        #pragma unroll
        for (int ch = 0; ch < 2; ++ch) {
            short8 af = *(const short8*)&gS[w][r16][ch * 32 + q * 8];
            #pragma unroll
            for (int tt = 0; tt < 8; ++tt)
                tacc[tt] = __builtin_amdgcn_mfma_f32_16x16x32_bf16(af, bpA[(tt * 2 + ch) * 64 + l], tacc[tt], 0, 0, 0);
        }
        if (q < 2) {
            #pragma unroll
            for (int tt = 0; tt < 8; ++tt) {
                float cb = cbias[tt * 16 + r16];
                #pragma unroll
                for (int rg = 0; rg < 4; ++rg)
                    tvS[w][q * 4 + rg][tt * 16 + r16] = f2bf(tacc[tt][rg] + cb);
            }
        }
    }

    for (int pp = 0; pp < 8; ++pp) {
        int n = nbase + pp;
        unsigned tvp = *(const unsigned*)&tvS[w][pp][c0];
        float tv0 = bf2f(tvp & 0xffffu), tv1 = bf2f(tvp >> 16);
        #pragma unroll
        for (int k = 0; k < 16; ++k) {
            float4 d4 = *(const float4*)&dxS[w][pp][k * 4];
            float s0 = tv0 + d4.x * we0.x + d4.y * we1.x + d4.z * we2.x;
            float s1 = tv1 + d4.x * we0.y + d4.y * we1.y + d4.z * we2.y;
            *(unsigned*)&gS[w][k][c0] = pack_bf2(gelu_f(s0), gelu_f(s1));
        }

        floatx4 acc[8];
        #pragma unroll
        for (int tt = 0; tt < 8; ++tt) acc[tt] = z4;
        #pragma unroll
        for (int ch = 0; ch < 4; ++ch) {
            short8 af = *(const short8*)&gS[w][r16][ch * 32 + q * 8];
            #pragma unroll
            for (int tt = 0; tt < 8; ++tt)
                acc[tt] = __builtin_amdgcn_mfma_f32_16x16x32_bf16(af, bfr[tt][ch], acc[tt], 0, 0, 0);
        }

        const int* idp = &idS[w][pp * 16];
        int i0 = idp[q * 4 + 0], i1 = idp[q * 4 + 1];
        int i2 = idp[q * 4 + 2], i3 = idp[q * 4 + 3];
        float keep0 = 0.f, keep1 = 0.f;
        #pragma unroll
        for (int tt = 0; tt < 8; ++tt) {
            int cb = tt * 16 + r16;
            float v0 = acc[tt].x + bf2f(xpb[(size_t)i0 * 128 + cb]);
            float v1 = acc[tt].y + bf2f(xpb[(size_t)i1 * 128 + cb]);
            float v2 = acc[tt].z + bf2f(xpb[(size_t)i2 * 128 + cb]);
            float v3 = acc[tt].w + bf2f(xpb[(size_t)i3 * 128 + cb]);
            float mx = fmaxf(fmaxf(v0, v1), fmaxf(v2, v3));
            mx = fmaxf(mx, __shfl_xor(mx, 16));
            mx = fmaxf(mx, __shfl_xor(mx, 32));
            if (tt == q)     keep0 = mx;
            if (tt == q + 4) keep1 = mx;
        }
        size_t base = (size_t)n * 128;
        float x0 = bf2f(xpb[base + l]), x1 = bf2f(xpb[base + l + 64]);
        feat[base + l]      += (keep0 + b3b0 - x0) * lg0 + lb0;
        feat[base + l + 64] += (keep1 + b3b1 - x1) * lg1 + lb1;
    }
}

// ---------------------------------------------------------------------------
extern "C" void kernel_launch(void* const* d_in, const int* in_sizes, int n_in,
                              void* d_out, int out_size, void* d_ws, size_t ws_size,
                              hipStream_t stream) {
    const float* x       = (const float*)d_in[0];
    const float* xyz     = (const float*)d_in[1];
    const float* g_pos   = (const float*)d_in[2];
    const float* ne_w1   = (const float*)d_in[3];
    const float* ne_g1   = (const float*)d_in[4];
    const float* ne_b1   = (const float*)d_in[5];
    const float* ne_w2   = (const float*)d_in[6];
    const float* ne_g2   = (const float*)d_in[7];
    const float* ne_b2   = (const float*)d_in[8];
    const float* ne_w3   = (const float*)d_in[9];
    const float* nbr_g   = (const float*)d_in[10];
    const float* nbr_b   = (const float*)d_in[11];
    const float* gpe_w   = (const float*)d_in[12];
    const float* bm_w1   = (const float*)d_in[13];
    const float* bm_b1   = (const float*)d_in[14];
    const float* bm_w2   = (const float*)d_in[15];
    const float* bm_g    = (const float*)d_in[16];
    const float* bm_b    = (const float*)d_in[17];
    const float* lfa_proj = (const float*)d_in[18];
    const float* lfa_g   = (const float*)d_in[19];
    const float* lfa_b   = (const float*)d_in[20];
    const float* nca_w1  = (const float*)d_in[21];
    const float* nca_b1  = (const float*)d_in[22];
    const float* nca_w2  = (const float*)d_in[23];
    const float* nca_b2  = (const float*)d_in[24];
    const float* nca_w3a = (const float*)d_in[25];
    const float* nca_b3a = (const float*)d_in[26];
    const float* nca_w3b = (const float*)d_in[27];
    const float* nca_b3b = (const float*)d_in[28];
    const float* m_w1    = (const float*)d_in[29];
    const float* m_b1    = (const float*)d_in[30];
    const float* m_w2    = (const float*)d_in[31];
    const float* m_g     = (const float*)d_in[32];
    const float* m_b     = (const float*)d_in[33];
    const float* pp_g    = (const float*)d_in[34];
    const float* pp_b    = (const float*)d_in[35];
    const float* pp_w    = (const float*)d_in[36];
    const int*   knn     = (const int*)d_in[37];

    float* ws    = (float*)d_ws;
    float* dxyz  = ws;                                   // N*48
    float* feat  = dxyz + (size_t)NPTS * 48;             // N*128
    float* Weff  = feat + (size_t)NPTS * 128;            // 1536
    float* cbias = Weff + 1536;                          // 512
    unsigned short* xpb    = (unsigned short*)(cbias + 512);    // N*128
    unsigned short* P_bm1  = xpb + (size_t)NPTS * 128;   // 32768
    unsigned short* P_bm2  = P_bm1 + 32768;              // 32768
    unsigned short* P_m1   = P_bm2 + 32768;              // 65536
    unsigned short* P_m2   = P_m1 + 65536;               // 65536
    unsigned short* P_proj = P_m2 + 65536;               // 65536
    unsigned short* P_pp   = P_proj + 65536;             // 32768
    unsigned short* P_w3a  = P_pp + 32768;               // 32768
    unsigned short* P_w3b  = P_w3a + 32768;              // 65536
    unsigned short* P_ne3  = P_w3b + 65536;              // 4096
    unsigned short* P_gpe  = P_ne3 + 4096;               // 8192
    unsigned short* P_ne1  = P_gpe + 8192;               // 512
    unsigned short* P_ne2  = P_ne1 + 512;                // 1024
    float* out = (float*)d_out;

    hipLaunchKernelGGL(precompute_kernel, dim3(4), dim3(128), 0, stream,
                       nca_w1, nca_b1, nca_w2, nca_b2, nca_w3a, nca_b3a, Weff, cbias);
    hipLaunchKernelGGL(pack_all, dim3(795), dim3(64), 0, stream,
                       bm_w1, bm_w2, m_w1, m_w2, lfa_proj, pp_w, nca_w3a, nca_w3b,
                       ne_w3, gpe_w, ne_w1, ne_g1, ne_w2, ne_g2,
                       P_bm1, P_bm2, P_m1, P_m2, P_proj, P_pp, P_w3a, P_w3b,
                       P_ne3, P_gpe, P_ne1, P_ne2);
    hipLaunchKernelGGL(nbr_embed_v2, dim3(1024), dim3(256), 0, stream,
                       x, xyz, knn, ne_b1, ne_b2, P_ne1, P_ne2, P_ne3,
                       nbr_g, nbr_b, dxyz, feat);
    hipLaunchKernelGGL(mlp_mfma, dim3(512), dim3(256), 0, stream,
                       feat, P_bm1, bm_b1, P_bm2, bm_g, bm_b,
                       P_gpe, g_pos, P_proj, xpb);
    for (int i = 0; i < 4; ++i) {
        hipLaunchKernelGGL(lfa_mfma4, dim3(1024), dim3(256), 0, stream,
                           feat, xpb, dxyz, knn,
                           nca_w1 + (size_t)i * 192, nca_b1 + (size_t)i * 64,
                           P_w3a + (size_t)i * 8192,
                           Weff + (size_t)i * 384, cbias + (size_t)i * 128,
                           P_w3b + (size_t)i * 16384,
                           nca_b3b + (size_t)i * 128,
                           lfa_g + (size_t)i * 128, lfa_b + (size_t)i * 128);
        if (i == 0 || i == 2) {
            hipLaunchKernelGGL(linear_mfma, dim3(512), dim3(256), 0, stream,
                               feat, P_proj + (size_t)(i + 1) * 16384, xpb);
        } else {
            int j = i >> 1;
            hipLaunchKernelGGL(mlp_mfma, dim3(512), dim3(256), 0, stream,
                               feat, P_m1 + (size_t)j * 32768, m_b1 + (size_t)j * 256,
                               P_m2 + (size_t)j * 32768, m_g + (size_t)j * 128,
                               m_b + (size_t)j * 128,
                               (const unsigned short*)nullptr, (const float*)nullptr,
                               (i == 1) ? (P_proj + (size_t)2 * 16384) : (const unsigned short*)nullptr,
                               xpb);
        }
    }
    hipLaunchKernelGGL(postproj_mfma, dim3(512), dim3(256), 0, stream,
                       out, feat, pp_g, pp_b, P_pp);
}

// Round 6
// 753.920 us; speedup vs baseline: 1.3240x; 1.3240x over previous
//
#include <hip/hip_runtime.h>
#include <math.h>

#define NPTS 32768
#define BN_RSQ 0.9999950000374997f

typedef __attribute__((ext_vector_type(8))) short short8;
typedef __attribute__((ext_vector_type(4))) float floatx4;

// Polynomial GELU (no transcendentals): gelu(x) = x * clamp01(0.5 + t*P(t^2)),
// t = clamp(x, -3, 3). Max abs err ~0.015, below bf16 quantization noise.
__device__ __forceinline__ float gelu_f(float v) {
    float t = fminf(fmaxf(v, -3.0f), 3.0f);
    float t2 = t * t;
    float p = fmaf(t2, fmaf(t2, fmaf(t2, -2.83231e-4f, 6.51008e-3f), -6.12871e-2f), 0.396958f);
    float phi = fmaf(t, p, 0.5f);
    phi = fminf(fmaxf(phi, 0.0f), 1.0f);
    return v * phi;
}
__device__ __forceinline__ unsigned short f2bf(float f) {
    unsigned u = __float_as_uint(f) + 0x8000u;
    return (unsigned short)(u >> 16);
}
// pack two floats to (bf16(hi)<<16)|bf16(lo) in 3 instrs (2 adds + v_perm)
__device__ __forceinline__ unsigned pack_bf2(float lo, float hi) {
    unsigned ul = __float_as_uint(lo) + 0x8000u;
    unsigned uh = __float_as_uint(hi) + 0x8000u;
    return __builtin_amdgcn_perm(uh, ul, 0x07060302u);
}
__device__ __forceinline__ float bf2f(unsigned u) {
    return __uint_as_float(u << 16);
}

// ---------------------------------------------------------------------------
// Folded matrices per depth: Weff[i] = w1@w2@w3a_top (3x128),
// cbias[i] = (b1@w2 + b2)@w3a_top + b3a (128)
// ---------------------------------------------------------------------------
__global__ __launch_bounds__(128) void precompute_kernel(
    const float* __restrict__ nca_w1, const float* __restrict__ nca_b1,
    const float* __restrict__ nca_w2, const float* __restrict__ nca_b2,
    const float* __restrict__ nca_w3a, const float* __restrict__ nca_b3a,
    float* __restrict__ Weff, float* __restrict__ cbias)
{
    int i = blockIdx.x;
    int t = threadIdx.x;
    const float* w1 = nca_w1 + i * 3 * 64;
    const float* b1 = nca_b1 + i * 64;
    const float* w2 = nca_w2 + i * 64 * 64;
    const float* b2 = nca_b2 + i * 64;
    const float* w3a = nca_w3a + i * 128 * 128;
    const float* b3a = nca_b3a + i * 128;

    __shared__ float u[3][64];
    __shared__ float v[64];
    if (t < 64) {
        for (int r = 0; r < 3; ++r) {
            float s = 0.f;
            for (int m = 0; m < 64; ++m) s += w1[r * 64 + m] * w2[m * 64 + t];
            u[r][t] = s;
        }
        float s = 0.f;
        for (int m = 0; m < 64; ++m) s += b1[m] * w2[m * 64 + t];
        v[t] = s + b2[t];
    }
    __syncthreads();
    for (int r = 0; r < 3; ++r) {
        float s = 0.f;
        for (int m = 0; m < 64; ++m) s += u[r][m] * w3a[m * 128 + t];
        Weff[i * 384 + r * 128 + t] = s;
    }
    {
        float s = 0.f;
        for (int m = 0; m < 64; ++m) s += v[m] * w3a[m * 128 + t];
        cbias[i * 128 + t] = s + b3a[t];
    }
}

// ---------------------------------------------------------------------------
// Generic B-fragment packer (bf16 MFMA B layout), zero-pad beyond Kr,
// optional per-column gamma fold.
// ---------------------------------------------------------------------------
__global__ __launch_bounds__(64) void pack_all(
    const float* __restrict__ bm_w1, const float* __restrict__ bm_w2,
    const float* __restrict__ m_w1, const float* __restrict__ m_w2,
    const float* __restrict__ lfa_proj, const float* __restrict__ pp_w,
    const float* __restrict__ nca_w3a, const float* __restrict__ nca_w3b,
    const float* __restrict__ ne_w3, const float* __restrict__ gpe_w,
    const float* __restrict__ ne_w1, const float* __restrict__ ne_g1,
    const float* __restrict__ ne_w2, const float* __restrict__ ne_g2,
    unsigned short* __restrict__ P_bm1, unsigned short* __restrict__ P_bm2,
    unsigned short* __restrict__ P_m1, unsigned short* __restrict__ P_m2,
    unsigned short* __restrict__ P_proj, unsigned short* __restrict__ P_pp,
    unsigned short* __restrict__ P_w3a, unsigned short* __restrict__ P_w3b,
    unsigned short* __restrict__ P_ne3, unsigned short* __restrict__ P_gpe,
    unsigned short* __restrict__ P_ne1, unsigned short* __restrict__ P_ne2)
{
    int b = blockIdx.x, l = threadIdx.x;
    const float* src; unsigned short* dst; int K, C, fb; int Kr = 0;
    const float* fold = nullptr;
    if (b < 64)       { src = bm_w1; dst = P_bm1; K = 128; C = 256; fb = b; }
    else if (b < 128) { src = bm_w2; dst = P_bm2; K = 256; C = 128; fb = b - 64; }
    else if (b < 256) { int i = (b - 128) >> 6; src = m_w1 + i * 32768; dst = P_m1 + i * 32768; K = 128; C = 256; fb = (b - 128) & 63; }
    else if (b < 384) { int i = (b - 256) >> 6; src = m_w2 + i * 32768; dst = P_m2 + i * 32768; K = 256; C = 128; fb = (b - 256) & 63; }
    else if (b < 512) { int i = (b - 384) >> 5; src = lfa_proj + i * 16384; dst = P_proj + i * 16384; K = 128; C = 128; fb = (b - 384) & 31; }
    else if (b < 576) { src = pp_w; dst = P_pp; K = 128; C = 256; fb = b - 512; }
    else if (b < 640) { int i = (b - 576) >> 4; src = nca_w3a + i * 16384 + 64 * 128; dst = P_w3a + i * 8192; K = 64; C = 128; fb = (b - 576) & 15; }
    else if (b < 768) { int i = (b - 640) >> 5; src = nca_w3b + i * 16384; dst = P_w3b + i * 16384; K = 128; C = 128; fb = (b - 640) & 31; }
    else if (b < 776) { src = ne_w3; dst = P_ne3; K = 32; C = 128; fb = b - 768; }
    else if (b < 792) { src = gpe_w; dst = P_gpe; K = 64; C = 128; fb = b - 776; }
    else if (b == 792){ src = ne_w1; dst = P_ne1; K = 32; C = 16; fb = 0; Kr = 10; fold = ne_g1; }
    else              { src = ne_w2; dst = P_ne2; K = 32; C = 32; fb = b - 793; Kr = 16; fold = ne_g2; }
    if (Kr == 0) Kr = K;
    int Kc = K >> 5;
    int tile = fb / Kc, chunk = fb % Kc;
    unsigned short* o = dst + ((size_t)fb * 64 + l) * 8;
    #pragma unroll
    for (int j = 0; j < 8; ++j) {
        int kk = chunk * 32 + (l >> 4) * 8 + j;
        int nn = tile * 16 + (l & 15);
        float v = 0.f;
        if (kk < Kr) {
            v = src[kk * C + nn];
            if (fold) v *= fold[nn] * BN_RSQ;
        }
        o[j] = f2bf(v);
    }
}

// ---------------------------------------------------------------------------
// Neighbor embedding: 4 independent waves/block, zero barriers, all 3 layers
// MFMA. grid 1024 x 256, 8 points/wave.
// ---------------------------------------------------------------------------
__global__ __launch_bounds__(256) void nbr_embed_v2(
    const float* __restrict__ x, const float* __restrict__ xyz,
    const int* __restrict__ knn,
    const float* __restrict__ ne_b1, const float* __restrict__ ne_b2,
    const unsigned short* __restrict__ P_ne1, const unsigned short* __restrict__ P_ne2,
    const unsigned short* __restrict__ P_ne3,
    const float* __restrict__ nbr_g, const float* __restrict__ nbr_b,
    float* __restrict__ dxyz_out, float* __restrict__ feat)
{
    int t = threadIdx.x, w = t >> 6, l = t & 63, q = l >> 4, r16 = l & 15;
    __shared__ __align__(16) unsigned short h1L[4][16][24];
    __shared__ __align__(16) unsigned short h2L[4][16][40];

    short8 B1 = ((const short8*)P_ne1)[l];
    short8 B2[2], B3[8];
    B2[0] = ((const short8*)P_ne2)[l];
    B2[1] = ((const short8*)P_ne2)[64 + l];
    #pragma unroll
    for (int tt = 0; tt < 8; ++tt) B3[tt] = ((const short8*)P_ne3)[tt * 64 + l];
    float b1r = ne_b1[r16];
    float b2r0 = ne_b2[r16], b2r1 = ne_b2[16 + r16];
    float bg0 = nbr_g[l] * BN_RSQ, bb0 = nbr_b[l];
    float bg1 = nbr_g[l + 64] * BN_RSQ, bb1 = nbr_b[l + 64];
    int nbase = blockIdx.x * 32 + w * 8;
    floatx4 z4 = {0.f, 0.f, 0.f, 0.f};

    for (int pp = 0; pp < 8; ++pp) {
        int n = nbase + pp;
        int id = knn[n * 16 + r16];
        float f0 = 0.f, f1 = 0.f, f2 = 0.f, f3 = 0.f, f4 = 0.f, f5 = 0.f, f6 = 0.f, f7 = 0.f;
        if (q == 0) {
            f0 = xyz[(size_t)id * 3 + 0] - xyz[(size_t)n * 3 + 0];
            f1 = xyz[(size_t)id * 3 + 1] - xyz[(size_t)n * 3 + 1];
            f2 = xyz[(size_t)id * 3 + 2] - xyz[(size_t)n * 3 + 2];
            dxyz_out[(size_t)n * 48 + r16 * 3 + 0] = f0;
            dxyz_out[(size_t)n * 48 + r16 * 3 + 1] = f1;
            dxyz_out[(size_t)n * 48 + r16 * 3 + 2] = f2;
            f3 = x[(size_t)id * 7 + 0]; f4 = x[(size_t)id * 7 + 1];
            f5 = x[(size_t)id * 7 + 2]; f6 = x[(size_t)id * 7 + 3];
            f7 = x[(size_t)id * 7 + 4];
        } else if (q == 1) {
            f0 = x[(size_t)id * 7 + 5]; f1 = x[(size_t)id * 7 + 6];
        }
        uint4 au = make_uint4(pack_bf2(f0, f1), pack_bf2(f2, f3),
                              pack_bf2(f4, f5), pack_bf2(f6, f7));
        short8 a1 = __builtin_bit_cast(short8, au);
        floatx4 c1 = __builtin_amdgcn_mfma_f32_16x16x32_bf16(a1, B1, z4, 0, 0, 0);
        #pragma unroll
        for (int rg = 0; rg < 4; ++rg)
            h1L[w][q * 4 + rg][r16] = f2bf(gelu_f(c1[rg] + b1r));

        short8 a2 = {0, 0, 0, 0, 0, 0, 0, 0};
        if (q < 2) a2 = *(const short8*)&h1L[w][r16][q * 8];
        #pragma unroll
        for (int nt = 0; nt < 2; ++nt) {
            floatx4 c2 = __builtin_amdgcn_mfma_f32_16x16x32_bf16(a2, B2[nt], z4, 0, 0, 0);
            float br = nt ? b2r1 : b2r0;
            #pragma unroll
            for (int rg = 0; rg < 4; ++rg)
                h2L[w][q * 4 + rg][nt * 16 + r16] = f2bf(gelu_f(c2[rg] + br));
        }

        short8 a3 = *(const short8*)&h2L[w][r16][q * 8];
        float keep0 = 0.f, keep1 = 0.f;
        #pragma unroll
        for (int tt = 0; tt < 8; ++tt) {
            floatx4 c3 = __builtin_amdgcn_mfma_f32_16x16x32_bf16(a3, B3[tt], z4, 0, 0, 0);
            float mx = fmaxf(fmaxf(c3.x, c3.y), fmaxf(c3.z, c3.w));
            mx = fmaxf(mx, __shfl_xor(mx, 16));
            mx = fmaxf(mx, __shfl_xor(mx, 32));
            if (tt == q)     keep0 = mx;
            if (tt == q + 4) keep1 = mx;
        }
        feat[(size_t)n * 128 + l]      = keep0 * bg0 + bb0;
        feat[(size_t)n * 128 + l + 64] = keep1 * bg1 + bb1;
    }
}

// ---------------------------------------------------------------------------
// Residual MLP via MFMA, optional fused gpe pre-pass and xp-projection tail.
// ---------------------------------------------------------------------------
__global__ __launch_bounds__(256, 2) void mlp_mfma(
    float* __restrict__ feat,
    const unsigned short* __restrict__ P1, const float* __restrict__ b1,
    const unsigned short* __restrict__ P2,
    const float* __restrict__ g, const float* __restrict__ b,
    const unsigned short* __restrict__ P_gpe, const float* __restrict__ g_pos,
    const unsigned short* __restrict__ P_proj, unsigned short* __restrict__ xpb)
{
    int t = threadIdx.x, w = t >> 6, l = t & 63;
    int q = l >> 4, r16 = l & 15;
    __shared__ __align__(16) unsigned short aS[16][136];
    __shared__ __align__(16) unsigned short hS[16][264];
    __shared__ __align__(16) float fS[16][132];

    const short8* B1 = (const short8*)P1;
    const short8* B2 = (const short8*)P2;
    short8 b1f[4][4];
    #pragma unroll
    for (int nt = 0; nt < 4; ++nt)
        #pragma unroll
        for (int ch = 0; ch < 4; ++ch)
            b1f[nt][ch] = B1[((w * 4 + nt) * 4 + ch) * 64 + l];
    short8 b2f[2][8];
    #pragma unroll
    for (int nt = 0; nt < 2; ++nt)
        #pragma unroll
        for (int ch = 0; ch < 8; ++ch)
            b2f[nt][ch] = B2[((w * 2 + nt) * 8 + ch) * 64 + l];
    float bb1[4];
    #pragma unroll
    for (int nt = 0; nt < 4; ++nt) bb1[nt] = b1[w * 64 + nt * 16 + r16];
    float gg[2], bb[2];
    #pragma unroll
    for (int nt = 0; nt < 2; ++nt) {
        int c = w * 32 + nt * 16 + r16;
        gg[nt] = g[c] * BN_RSQ; bb[nt] = b[c];
    }
    floatx4 z4 = {0.f, 0.f, 0.f, 0.f};

    for (int itc = 0; itc < 4; ++itc) {
        int n0 = blockIdx.x * 64 + itc * 16;
        {
            int row = t >> 4, c8 = (t & 15) * 8;
            float4 fa = *(const float4*)&feat[(size_t)(n0 + row) * 128 + c8];
            float4 fb4 = *(const float4*)&feat[(size_t)(n0 + row) * 128 + c8 + 4];
            *(float4*)&fS[row][c8] = fa;
            *(float4*)&fS[row][c8 + 4] = fb4;
            if (!P_gpe) {
                *(uint4*)&aS[row][c8] = make_uint4(
                    pack_bf2(fa.x, fa.y), pack_bf2(fa.z, fa.w),
                    pack_bf2(fb4.x, fb4.y), pack_bf2(fb4.z, fb4.w));
            }
        }
        __syncthreads();

        if (P_gpe) {
            const short8* Bg = (const short8*)P_gpe;
            floatx4 cg[2] = {z4, z4};
            #pragma unroll
            for (int ch = 0; ch < 2; ++ch) {
                const float* gp = &g_pos[(size_t)(n0 + r16) * 64 + ch * 32 + q * 8];
                float4 ga = *(const float4*)gp;
                float4 gb4 = *(const float4*)(gp + 4);
                uint4 au = make_uint4(pack_bf2(ga.x, ga.y), pack_bf2(ga.z, ga.w),
                                      pack_bf2(gb4.x, gb4.y), pack_bf2(gb4.z, gb4.w));
                short8 ag = __builtin_bit_cast(short8, au);
                #pragma unroll
                for (int nt = 0; nt < 2; ++nt)
                    cg[nt] = __builtin_amdgcn_mfma_f32_16x16x32_bf16(ag, Bg[((2 * w + nt) * 2 + ch) * 64 + l], cg[nt], 0, 0, 0);
            }
            #pragma unroll
            for (int nt = 0; nt < 2; ++nt) {
                int c = (2 * w + nt) * 16 + r16;
                #pragma unroll
                for (int rg = 0; rg < 4; ++rg) {
                    int row = q * 4 + rg;
                    float v = fS[row][c] + cg[nt][rg];
                    fS[row][c] = v;
                    aS[row][c] = f2bf(v);
                }
            }
            __syncthreads();
        }

        floatx4 acc1[4];
        #pragma unroll
        for (int nt = 0; nt < 4; ++nt) acc1[nt] = z4;
        #pragma unroll
        for (int ch = 0; ch < 4; ++ch) {
            short8 af = *(const short8*)&aS[r16][ch * 32 + q * 8];
            #pragma unroll
            for (int nt = 0; nt < 4; ++nt)
                acc1[nt] = __builtin_amdgcn_mfma_f32_16x16x32_bf16(af, b1f[nt][ch], acc1[nt], 0, 0, 0);
        }
        #pragma unroll
        for (int nt = 0; nt < 4; ++nt) {
            int c = w * 64 + nt * 16 + r16;
            #pragma unroll
            for (int rg = 0; rg < 4; ++rg)
                hS[q * 4 + rg][c] = f2bf(gelu_f(acc1[nt][rg] + bb1[nt]));
        }
        __syncthreads();

        floatx4 acc2[2];
        #pragma unroll
        for (int nt = 0; nt < 2; ++nt) acc2[nt] = z4;
        #pragma unroll
        for (int ch = 0; ch < 8; ++ch) {
            short8 af = *(const short8*)&hS[r16][ch * 32 + q * 8];
            #pragma unroll
            for (int nt = 0; nt < 2; ++nt)
                acc2[nt] = __builtin_amdgcn_mfma_f32_16x16x32_bf16(af, b2f[nt][ch], acc2[nt], 0, 0, 0);
        }
        #pragma unroll
        for (int nt = 0; nt < 2; ++nt) {
            int c = w * 32 + nt * 16 + r16;
            #pragma unroll
            for (int rg = 0; rg < 4; ++rg) {
                int row = q * 4 + rg;
                float v = fS[row][c] + acc2[nt][rg] * gg[nt] + bb[nt];
                feat[(size_t)(n0 + row) * 128 + c] = v;
                if (P_proj) aS[row][c] = f2bf(v);
            }
        }
        if (P_proj) {
            __syncthreads();
            const short8* Bp = (const short8*)P_proj;
            #pragma unroll
            for (int nt = 0; nt < 2; ++nt) {
                int tg = w * 2 + nt;
                floatx4 ap = z4;
                #pragma unroll
                for (int ch = 0; ch < 4; ++ch) {
                    short8 af = *(const short8*)&aS[r16][ch * 32 + q * 8];
                    ap = __builtin_amdgcn_mfma_f32_16x16x32_bf16(af, Bp[(tg * 4 + ch) * 64 + l], ap, 0, 0, 0);
                }
                #pragma unroll
                for (int rg = 0; rg < 4; ++rg)
                    xpb[(size_t)(n0 + q * 4 + rg) * 128 + tg * 16 + r16] = f2bf(ap[rg]);
            }
        }
        __syncthreads();
    }
}

// ---------------------------------------------------------------------------
// xp = feat @ proj (128->128), bf16 output (depths 1,3).
// ---------------------------------------------------------------------------
__global__ __launch_bounds__(256) void linear_mfma(
    const float* __restrict__ feat, const unsigned short* __restrict__ P,
    unsigned short* __restrict__ xp)
{
    int t = threadIdx.x, w = t >> 6, l = t & 63;
    int q = l >> 4, r16 = l & 15;
    __shared__ __align__(16) unsigned short aS[16][136];
    const short8* B = (const short8*)P;
    short8 bf[2][4];
    #pragma unroll
    for (int nt = 0; nt < 2; ++nt)
        #pragma unroll
        for (int ch = 0; ch < 4; ++ch)
            bf[nt][ch] = B[((w * 2 + nt) * 4 + ch) * 64 + l];
    floatx4 z4 = {0.f, 0.f, 0.f, 0.f};

    for (int itc = 0; itc < 4; ++itc) {
        int n0 = blockIdx.x * 64 + itc * 16;
        {
            int row = t >> 4, c8 = (t & 15) * 8;
            float4 fa = *(const float4*)&feat[(size_t)(n0 + row) * 128 + c8];
            float4 fb4 = *(const float4*)&feat[(size_t)(n0 + row) * 128 + c8 + 4];
            *(uint4*)&aS[row][c8] = make_uint4(
                pack_bf2(fa.x, fa.y), pack_bf2(fa.z, fa.w),
                pack_bf2(fb4.x, fb4.y), pack_bf2(fb4.z, fb4.w));
        }
        __syncthreads();
        floatx4 acc[2];
        #pragma unroll
        for (int nt = 0; nt < 2; ++nt) acc[nt] = z4;
        #pragma unroll
        for (int ch = 0; ch < 4; ++ch) {
            short8 af = *(const short8*)&aS[r16][ch * 32 + q * 8];
            #pragma unroll
            for (int nt = 0; nt < 2; ++nt)
                acc[nt] = __builtin_amdgcn_mfma_f32_16x16x32_bf16(af, bf[nt][ch], acc[nt], 0, 0, 0);
        }
        #pragma unroll
        for (int nt = 0; nt < 2; ++nt) {
            int c = w * 32 + nt * 16 + r16;
            #pragma unroll
            for (int rg = 0; rg < 4; ++rg)
                xp[(size_t)(n0 + q * 4 + rg) * 128 + c] = f2bf(acc[nt][rg]);
        }
        __syncthreads();
    }
}

// ---------------------------------------------------------------------------
// Postproj: out = BN(feat) @ pp_w (128->256), fp32 out.
// ---------------------------------------------------------------------------
__global__ __launch_bounds__(256) void postproj_mfma(
    float* __restrict__ out, const float* __restrict__ feat,
    const float* __restrict__ g, const float* __restrict__ b,
    const unsigned short* __restrict__ P)
{
    int t = threadIdx.x, w = t >> 6, l = t & 63;
    int q = l >> 4, r16 = l & 15;
    __shared__ __align__(16) unsigned short aS[16][136];
    const short8* B = (const short8*)P;
    short8 bf[4][4];
    #pragma unroll
    for (int nt = 0; nt < 4; ++nt)
        #pragma unroll
        for (int ch = 0; ch < 4; ++ch)
            bf[nt][ch] = B[((w * 4 + nt) * 4 + ch) * 64 + l];
    floatx4 z4 = {0.f, 0.f, 0.f, 0.f};

    for (int itc = 0; itc < 4; ++itc) {
        int n0 = blockIdx.x * 64 + itc * 16;
        {
            int row = t >> 4, c8 = (t & 15) * 8;
            const float* fp = &feat[(size_t)(n0 + row) * 128 + c8];
            float4 fa = *(const float4*)fp;
            float4 fb4 = *(const float4*)(fp + 4);
            float4 ga = *(const float4*)&g[c8], gb4 = *(const float4*)&g[c8 + 4];
            float4 ba = *(const float4*)&b[c8], bb4 = *(const float4*)&b[c8 + 4];
            *(uint4*)&aS[row][c8] = make_uint4(
                pack_bf2(fa.x * ga.x * BN_RSQ + ba.x, fa.y * ga.y * BN_RSQ + ba.y),
                pack_bf2(fa.z * ga.z * BN_RSQ + ba.z, fa.w * ga.w * BN_RSQ + ba.w),
                pack_bf2(fb4.x * gb4.x * BN_RSQ + bb4.x, fb4.y * gb4.y * BN_RSQ + bb4.y),
                pack_bf2(fb4.z * gb4.z * BN_RSQ + bb4.z, fb4.w * gb4.w * BN_RSQ + bb4.w));
        }
        __syncthreads();
        floatx4 acc[4];
        #pragma unroll
        for (int nt = 0; nt < 4; ++nt) acc[nt] = z4;
        #pragma unroll
        for (int ch = 0; ch < 4; ++ch) {
            short8 af = *(const short8*)&aS[r16][ch * 32 + q * 8];
            #pragma unroll
            for (int nt = 0; nt < 4; ++nt)
                acc[nt] = __builtin_amdgcn_mfma_f32_16x16x32_bf16(af, bf[nt][ch], acc[nt], 0, 0, 0);
        }
        #pragma unroll
        for (int nt = 0; nt < 4; ++nt) {
            int c = w * 64 + nt * 16 + r16;
            #pragma unroll
            for (int rg = 0; rg < 4; ++rg)
                out[(size_t)(n0 + q * 4 + rg) * 256 + c] = acc[nt][rg];
        }
        __syncthreads();
    }
}

// ---------------------------------------------------------------------------
// LFA v6: R4 structure (launch_bounds(256,2) — 120 VGPR, NO spill; the (256,4)
// cap in R5 forced 64 VGPR and catastrophic scratch spill) + R5's poly GELU,
// pack_bf2, and LDS union (36.1 KB).
// ---------------------------------------------------------------------------
__global__ __launch_bounds__(256, 2) void lfa_mfma4(
    float* __restrict__ feat, const unsigned short* __restrict__ xpb,
    const float* __restrict__ dxyz, const int* __restrict__ knn,
    const float* __restrict__ w1, const float* __restrict__ b1,
    const unsigned short* __restrict__ P_w3a, const float* __restrict__ Weff,
    const float* __restrict__ cbias, const unsigned short* __restrict__ P_w3b,
    const float* __restrict__ b3b,
    const float* __restrict__ lg, const float* __restrict__ lb)
{
    int w = threadIdx.x >> 6, l = threadIdx.x & 63;
    int q = l >> 4, r16 = l & 15;

    __shared__ __align__(16) float dxS[4][8][64];
    __shared__ __align__(16) unsigned short tvS[4][8][132];
    // gS doubles as: phase A = p_local rows (points 0..7, cols 0..63);
    // phase B = GELU(a) rows (neighbors 0..15, cols 0..127).
    __shared__ __align__(16) unsigned short gS[4][16][136];
    __shared__ int idS[4][128];

    int nbase = blockIdx.x * 32 + w * 8;

    #pragma unroll
    for (int i = 0; i < 2; ++i)
        idS[w][i * 64 + l] = knn[(size_t)nbase * 16 + i * 64 + l];
    #pragma unroll
    for (int i = 0; i < 6; ++i) {
        int gI = i * 64 + l;                 // 0..383
        int p = gI / 48, rr = gI % 48;
        int k = rr / 3, d = rr - k * 3;
        dxS[w][p][k * 4 + d] = dxyz[(size_t)nbase * 48 + gI];
    }

    short8 bfr[8][4];
    {
        const short8* bp = (const short8*)P_w3b;
        #pragma unroll
        for (int tt = 0; tt < 8; ++tt)
            #pragma unroll
            for (int ch = 0; ch < 4; ++ch)
                bfr[tt][ch] = bp[(tt * 4 + ch) * 64 + l];
    }
    int c0 = 2 * l;
    float2 we0 = *(const float2*)&Weff[c0];
    float2 we1 = *(const float2*)&Weff[128 + c0];
    float2 we2 = *(const float2*)&Weff[256 + c0];
    float w1r0 = w1[l], w1r1 = w1[64 + l], w1r2 = w1[128 + l], b1l = b1[l];
    float b3b0 = b3b[l], b3b1 = b3b[l + 64];
    float lg0 = lg[l] * BN_RSQ, lg1 = lg[l + 64] * BN_RSQ;
    float lb0 = lb[l], lb1 = lb[l + 64];
    floatx4 z4 = {0.f, 0.f, 0.f, 0.f};

    // phase A: p_local for 8 points into gS rows 0..7 (lane l owns hidden dim l)
    for (int p = 0; p < 8; ++p) {
        float m = -1e30f;
        #pragma unroll
        for (int k = 0; k < 16; ++k) {
            float4 d4 = *(const float4*)&dxS[w][p][k * 4];
            m = fmaxf(m, b1l + d4.x * w1r0 + d4.y * w1r1 + d4.z * w1r2);
        }
        gS[w][p][l] = f2bf(m);
    }

    // tv = cbias + pl @ w3a_bot : rows 8-15 garbage, discarded via q<2
    {
        floatx4 tacc[8];
        #pragma unroll
        for (int tt = 0; tt < 8; ++tt) tacc[tt] = z4;
        const short8* bpA = (const short8*)P_w3a;
        #pragma unroll
        for (int ch = 0; ch < 2; ++ch) {
            short8 af = *(const short8*)&gS[w][r16][ch * 32 + q * 8];
            #pragma unroll
            for (int tt = 0; tt < 8; ++tt)
                tacc[tt] = __builtin_amdgcn_mfma_f32_16x16x32_bf16(af, bpA[(tt * 2 + ch) * 64 + l], tacc[tt], 0, 0, 0);
        }
        if (q < 2) {
            #pragma unroll
            for (int tt = 0; tt < 8; ++tt) {
                float cb = cbias[tt * 16 + r16];
                #pragma unroll
                for (int rg = 0; rg < 4; ++rg)
                    tvS[w][q * 4 + rg][tt * 16 + r16] = f2bf(tacc[tt][rg] + cb);
            }
        }
    }

    for (int pp = 0; pp < 8; ++pp) {
        int n = nbase + pp;
        unsigned tvp = *(const unsigned*)&tvS[w][pp][c0];
        float tv0 = bf2f(tvp & 0xffffu), tv1 = bf2f(tvp >> 16);
        #pragma unroll
        for (int k = 0; k < 16; ++k) {
            float4 d4 = *(const float4*)&dxS[w][pp][k * 4];
            float s0 = tv0 + d4.x * we0.x + d4.y * we1.x + d4.z * we2.x;
            float s1 = tv1 + d4.x * we0.y + d4.y * we1.y + d4.z * we2.y;
            *(unsigned*)&gS[w][k][c0] = pack_bf2(gelu_f(s0), gelu_f(s1));
        }

        floatx4 acc[8];
        #pragma unroll
        for (int tt = 0; tt < 8; ++tt) acc[tt] = z4;
        #pragma unroll
        for (int ch = 0; ch < 4; ++ch) {
            short8 af = *(const short8*)&gS[w][r16][ch * 32 + q * 8];
            #pragma unroll
            for (int tt = 0; tt < 8; ++tt)
                acc[tt] = __builtin_amdgcn_mfma_f32_16x16x32_bf16(af, bfr[tt][ch], acc[tt], 0, 0, 0);
        }

        const int* idp = &idS[w][pp * 16];
        int i0 = idp[q * 4 + 0], i1 = idp[q * 4 + 1];
        int i2 = idp[q * 4 + 2], i3 = idp[q * 4 + 3];
        float keep0 = 0.f, keep1 = 0.f;
        #pragma unroll
        for (int tt = 0; tt < 8; ++tt) {
            int cb = tt * 16 + r16;
            float v0 = acc[tt].x + bf2f(xpb[(size_t)i0 * 128 + cb]);
            float v1 = acc[tt].y + bf2f(xpb[(size_t)i1 * 128 + cb]);
            float v2 = acc[tt].z + bf2f(xpb[(size_t)i2 * 128 + cb]);
            float v3 = acc[tt].w + bf2f(xpb[(size_t)i3 * 128 + cb]);
            float mx = fmaxf(fmaxf(v0, v1), fmaxf(v2, v3));
            mx = fmaxf(mx, __shfl_xor(mx, 16));
            mx = fmaxf(mx, __shfl_xor(mx, 32));
            if (tt == q)     keep0 = mx;
            if (tt == q + 4) keep1 = mx;
        }
        size_t base = (size_t)n * 128;
        float x0 = bf2f(xpb[base + l]), x1 = bf2f(xpb[base + l + 64]);
        feat[base + l]      += (keep0 + b3b0 - x0) * lg0 + lb0;
        feat[base + l + 64] += (keep1 + b3b1 - x1) * lg1 + lb1;
    }
}

// ---------------------------------------------------------------------------
extern "C" void kernel_launch(void* const* d_in, const int* in_sizes, int n_in,
                              void* d_out, int out_size, void* d_ws, size_t ws_size,
                              hipStream_t stream) {
    const float* x       = (const float*)d_in[0];
    const float* xyz     = (const float*)d_in[1];
    const float* g_pos   = (const float*)d_in[2];
    const float* ne_w1   = (const float*)d_in[3];
    const float* ne_g1   = (const float*)d_in[4];
    const float* ne_b1   = (const float*)d_in[5];
    const float* ne_w2   = (const float*)d_in[6];
    const float* ne_g2   = (const float*)d_in[7];
    const float* ne_b2   = (const float*)d_in[8];
    const float* ne_w3   = (const float*)d_in[9];
    const float* nbr_g   = (const float*)d_in[10];
    const float* nbr_b   = (const float*)d_in[11];
    const float* gpe_w   = (const float*)d_in[12];
    const float* bm_w1   = (const float*)d_in[13];
    const float* bm_b1   = (const float*)d_in[14];
    const float* bm_w2   = (const float*)d_in[15];
    const float* bm_g    = (const float*)d_in[16];
    const float* bm_b    = (const float*)d_in[17];
    const float* lfa_proj = (const float*)d_in[18];
    const float* lfa_g   = (const float*)d_in[19];
    const float* lfa_b   = (const float*)d_in[20];
    const float* nca_w1  = (const float*)d_in[21];
    const float* nca_b1  = (const float*)d_in[22];
    const float* nca_w2  = (const float*)d_in[23];
    const float* nca_b2  = (const float*)d_in[24];
    const float* nca_w3a = (const float*)d_in[25];
    const float* nca_b3a = (const float*)d_in[26];
    const float* nca_w3b = (const float*)d_in[27];
    const float* nca_b3b = (const float*)d_in[28];
    const float* m_w1    = (const float*)d_in[29];
    const float* m_b1    = (const float*)d_in[30];
    const float* m_w2    = (const float*)d_in[31];
    const float* m_g     = (const float*)d_in[32];
    const float* m_b     = (const float*)d_in[33];
    const float* pp_g    = (const float*)d_in[34];
    const float* pp_b    = (const float*)d_in[35];
    const float* pp_w    = (const float*)d_in[36];
    const int*   knn     = (const int*)d_in[37];

    float* ws    = (float*)d_ws;
    float* dxyz  = ws;                                   // N*48
    float* feat  = dxyz + (size_t)NPTS * 48;             // N*128
    float* Weff  = feat + (size_t)NPTS * 128;            // 1536
    float* cbias = Weff + 1536;                          // 512
    unsigned short* xpb    = (unsigned short*)(cbias + 512);    // N*128
    unsigned short* P_bm1  = xpb + (size_t)NPTS * 128;   // 32768
    unsigned short* P_bm2  = P_bm1 + 32768;              // 32768
    unsigned short* P_m1   = P_bm2 + 32768;              // 65536
    unsigned short* P_m2   = P_m1 + 65536;               // 65536
    unsigned short* P_proj = P_m2 + 65536;               // 65536
    unsigned short* P_pp   = P_proj + 65536;             // 32768
    unsigned short* P_w3a  = P_pp + 32768;               // 32768
    unsigned short* P_w3b  = P_w3a + 32768;              // 65536
    unsigned short* P_ne3  = P_w3b + 65536;              // 4096
    unsigned short* P_gpe  = P_ne3 + 4096;               // 8192
    unsigned short* P_ne1  = P_gpe + 8192;               // 512
    unsigned short* P_ne2  = P_ne1 + 512;                // 1024
    float* out = (float*)d_out;

    hipLaunchKernelGGL(precompute_kernel, dim3(4), dim3(128), 0, stream,
                       nca_w1, nca_b1, nca_w2, nca_b2, nca_w3a, nca_b3a, Weff, cbias);
    hipLaunchKernelGGL(pack_all, dim3(795), dim3(64), 0, stream,
                       bm_w1, bm_w2, m_w1, m_w2, lfa_proj, pp_w, nca_w3a, nca_w3b,
                       ne_w3, gpe_w, ne_w1, ne_g1, ne_w2, ne_g2,
                       P_bm1, P_bm2, P_m1, P_m2, P_proj, P_pp, P_w3a, P_w3b,
                       P_ne3, P_gpe, P_ne1, P_ne2);
    hipLaunchKernelGGL(nbr_embed_v2, dim3(1024), dim3(256), 0, stream,
                       x, xyz, knn, ne_b1, ne_b2, P_ne1, P_ne2, P_ne3,
                       nbr_g, nbr_b, dxyz, feat);
    hipLaunchKernelGGL(mlp_mfma, dim3(512), dim3(256), 0, stream,
                       feat, P_bm1, bm_b1, P_bm2, bm_g, bm_b,
                       P_gpe, g_pos, P_proj, xpb);
    for (int i = 0; i < 4; ++i) {
        hipLaunchKernelGGL(lfa_mfma4, dim3(1024), dim3(256), 0, stream,
                           feat, xpb, dxyz, knn,
                           nca_w1 + (size_t)i * 192, nca_b1 + (size_t)i * 64,
                           P_w3a + (size_t)i * 8192,
                           Weff + (size_t)i * 384, cbias + (size_t)i * 128,
                           P_w3b + (size_t)i * 16384,
                           nca_b3b + (size_t)i * 128,
                           lfa_g + (size_t)i * 128, lfa_b + (size_t)i * 128);
        if (i == 0 || i == 2) {
            hipLaunchKernelGGL(linear_mfma, dim3(512), dim3(256), 0, stream,
                               feat, P_proj + (size_t)(i + 1) * 16384, xpb);
        } else {
            int j = i >> 1;
            hipLaunchKernelGGL(mlp_mfma, dim3(512), dim3(256), 0, stream,
                               feat, P_m1 + (size_t)j * 32768, m_b1 + (size_t)j * 256,
                               P_m2 + (size_t)j * 32768, m_g + (size_t)j * 128,
                               m_b + (size_t)j * 128,
                               (const unsigned short*)nullptr, (const float*)nullptr,
                               (i == 1) ? (P_proj + (size_t)2 * 16384) : (const unsigned short*)nullptr,
                               xpb);
        }
    }
    hipLaunchKernelGGL(postproj_mfma, dim3(512), dim3(256), 0, stream,
                       out, feat, pp_g, pp_b, P_pp);
}

// Round 7
// 509.984 us; speedup vs baseline: 1.9574x; 1.4783x over previous
//
#include <hip/hip_runtime.h>
#include <math.h>

#define NPTS 32768
#define BN_RSQ 0.9999950000374997f

typedef __attribute__((ext_vector_type(8))) short short8;
typedef __attribute__((ext_vector_type(4))) float floatx4;

// Polynomial GELU (used in non-lfa kernels; measured neutral there).
__device__ __forceinline__ float gelu_f(float v) {
    float t = fminf(fmaxf(v, -3.0f), 3.0f);
    float t2 = t * t;
    float p = fmaf(t2, fmaf(t2, fmaf(t2, -2.83231e-4f, 6.51008e-3f), -6.12871e-2f), 0.396958f);
    float phi = fmaf(t, p, 0.5f);
    phi = fminf(fmaxf(phi, 0.0f), 1.0f);
    return v * phi;
}
__device__ __forceinline__ unsigned short f2bf(float f) {
    unsigned u = __float_as_uint(f) + 0x8000u;
    return (unsigned short)(u >> 16);
}
__device__ __forceinline__ unsigned pack_bf2(float lo, float hi) {
    unsigned ul = __float_as_uint(lo) + 0x8000u;
    unsigned uh = __float_as_uint(hi) + 0x8000u;
    return __builtin_amdgcn_perm(uh, ul, 0x07060302u);
}
__device__ __forceinline__ float bf2f(unsigned u) {
    return __uint_as_float(u << 16);
}

// --- lfa-local helpers: EXACT R4 versions (do not share with other kernels) ---
__device__ __forceinline__ float gelu_lfa(float v) {
    float c = v * v;
    float z = v * (1.5957691f + 0.07135685f * c);
    float s = __builtin_amdgcn_rcpf(1.0f + __expf(-z));
    return v * s;
}
__device__ __forceinline__ unsigned short f2bf_lfa(float f) {
    unsigned u = __float_as_uint(f);
    u += 0x7fffu + ((u >> 16) & 1u);
    return (unsigned short)(u >> 16);
}

// ---------------------------------------------------------------------------
// Folded matrices per depth: Weff[i] = w1@w2@w3a_top (3x128),
// cbias[i] = (b1@w2 + b2)@w3a_top + b3a (128)
// ---------------------------------------------------------------------------
__global__ __launch_bounds__(128) void precompute_kernel(
    const float* __restrict__ nca_w1, const float* __restrict__ nca_b1,
    const float* __restrict__ nca_w2, const float* __restrict__ nca_b2,
    const float* __restrict__ nca_w3a, const float* __restrict__ nca_b3a,
    float* __restrict__ Weff, float* __restrict__ cbias)
{
    int i = blockIdx.x;
    int t = threadIdx.x;
    const float* w1 = nca_w1 + i * 3 * 64;
    const float* b1 = nca_b1 + i * 64;
    const float* w2 = nca_w2 + i * 64 * 64;
    const float* b2 = nca_b2 + i * 64;
    const float* w3a = nca_w3a + i * 128 * 128;
    const float* b3a = nca_b3a + i * 128;

    __shared__ float u[3][64];
    __shared__ float v[64];
    if (t < 64) {
        for (int r = 0; r < 3; ++r) {
            float s = 0.f;
            for (int m = 0; m < 64; ++m) s += w1[r * 64 + m] * w2[m * 64 + t];
            u[r][t] = s;
        }
        float s = 0.f;
        for (int m = 0; m < 64; ++m) s += b1[m] * w2[m * 64 + t];
        v[t] = s + b2[t];
    }
    __syncthreads();
    for (int r = 0; r < 3; ++r) {
        float s = 0.f;
        for (int m = 0; m < 64; ++m) s += u[r][m] * w3a[m * 128 + t];
        Weff[i * 384 + r * 128 + t] = s;
    }
    {
        float s = 0.f;
        for (int m = 0; m < 64; ++m) s += v[m] * w3a[m * 128 + t];
        cbias[i * 128 + t] = s + b3a[t];
    }
}

// ---------------------------------------------------------------------------
// Generic B-fragment packer (bf16 MFMA B layout), zero-pad beyond Kr,
// optional per-column gamma fold.
// ---------------------------------------------------------------------------
__global__ __launch_bounds__(64) void pack_all(
    const float* __restrict__ bm_w1, const float* __restrict__ bm_w2,
    const float* __restrict__ m_w1, const float* __restrict__ m_w2,
    const float* __restrict__ lfa_proj, const float* __restrict__ pp_w,
    const float* __restrict__ nca_w3a, const float* __restrict__ nca_w3b,
    const float* __restrict__ ne_w3, const float* __restrict__ gpe_w,
    const float* __restrict__ ne_w1, const float* __restrict__ ne_g1,
    const float* __restrict__ ne_w2, const float* __restrict__ ne_g2,
    unsigned short* __restrict__ P_bm1, unsigned short* __restrict__ P_bm2,
    unsigned short* __restrict__ P_m1, unsigned short* __restrict__ P_m2,
    unsigned short* __restrict__ P_proj, unsigned short* __restrict__ P_pp,
    unsigned short* __restrict__ P_w3a, unsigned short* __restrict__ P_w3b,
    unsigned short* __restrict__ P_ne3, unsigned short* __restrict__ P_gpe,
    unsigned short* __restrict__ P_ne1, unsigned short* __restrict__ P_ne2)
{
    int b = blockIdx.x, l = threadIdx.x;
    const float* src; unsigned short* dst; int K, C, fb; int Kr = 0;
    const float* fold = nullptr;
    if (b < 64)       { src = bm_w1; dst = P_bm1; K = 128; C = 256; fb = b; }
    else if (b < 128) { src = bm_w2; dst = P_bm2; K = 256; C = 128; fb = b - 64; }
    else if (b < 256) { int i = (b - 128) >> 6; src = m_w1 + i * 32768; dst = P_m1 + i * 32768; K = 128; C = 256; fb = (b - 128) & 63; }
    else if (b < 384) { int i = (b - 256) >> 6; src = m_w2 + i * 32768; dst = P_m2 + i * 32768; K = 256; C = 128; fb = (b - 256) & 63; }
    else if (b < 512) { int i = (b - 384) >> 5; src = lfa_proj + i * 16384; dst = P_proj + i * 16384; K = 128; C = 128; fb = (b - 384) & 31; }
    else if (b < 576) { src = pp_w; dst = P_pp; K = 128; C = 256; fb = b - 512; }
    else if (b < 640) { int i = (b - 576) >> 4; src = nca_w3a + i * 16384 + 64 * 128; dst = P_w3a + i * 8192; K = 64; C = 128; fb = (b - 576) & 15; }
    else if (b < 768) { int i = (b - 640) >> 5; src = nca_w3b + i * 16384; dst = P_w3b + i * 16384; K = 128; C = 128; fb = (b - 640) & 31; }
    else if (b < 776) { src = ne_w3; dst = P_ne3; K = 32; C = 128; fb = b - 768; }
    else if (b < 792) { src = gpe_w; dst = P_gpe; K = 64; C = 128; fb = b - 776; }
    else if (b == 792){ src = ne_w1; dst = P_ne1; K = 32; C = 16; fb = 0; Kr = 10; fold = ne_g1; }
    else              { src = ne_w2; dst = P_ne2; K = 32; C = 32; fb = b - 793; Kr = 16; fold = ne_g2; }
    if (Kr == 0) Kr = K;
    int Kc = K >> 5;
    int tile = fb / Kc, chunk = fb % Kc;
    unsigned short* o = dst + ((size_t)fb * 64 + l) * 8;
    #pragma unroll
    for (int j = 0; j < 8; ++j) {
        int kk = chunk * 32 + (l >> 4) * 8 + j;
        int nn = tile * 16 + (l & 15);
        float v = 0.f;
        if (kk < Kr) {
            v = src[kk * C + nn];
            if (fold) v *= fold[nn] * BN_RSQ;
        }
        o[j] = f2bf(v);
    }
}

// ---------------------------------------------------------------------------
// Neighbor embedding: 4 independent waves/block, zero barriers, all 3 layers
// MFMA. grid 1024 x 256, 8 points/wave.
// ---------------------------------------------------------------------------
__global__ __launch_bounds__(256) void nbr_embed_v2(
    const float* __restrict__ x, const float* __restrict__ xyz,
    const int* __restrict__ knn,
    const float* __restrict__ ne_b1, const float* __restrict__ ne_b2,
    const unsigned short* __restrict__ P_ne1, const unsigned short* __restrict__ P_ne2,
    const unsigned short* __restrict__ P_ne3,
    const float* __restrict__ nbr_g, const float* __restrict__ nbr_b,
    float* __restrict__ dxyz_out, float* __restrict__ feat)
{
    int t = threadIdx.x, w = t >> 6, l = t & 63, q = l >> 4, r16 = l & 15;
    __shared__ __align__(16) unsigned short h1L[4][16][24];
    __shared__ __align__(16) unsigned short h2L[4][16][40];

    short8 B1 = ((const short8*)P_ne1)[l];
    short8 B2[2], B3[8];
    B2[0] = ((const short8*)P_ne2)[l];
    B2[1] = ((const short8*)P_ne2)[64 + l];
    #pragma unroll
    for (int tt = 0; tt < 8; ++tt) B3[tt] = ((const short8*)P_ne3)[tt * 64 + l];
    float b1r = ne_b1[r16];
    float b2r0 = ne_b2[r16], b2r1 = ne_b2[16 + r16];
    float bg0 = nbr_g[l] * BN_RSQ, bb0 = nbr_b[l];
    float bg1 = nbr_g[l + 64] * BN_RSQ, bb1 = nbr_b[l + 64];
    int nbase = blockIdx.x * 32 + w * 8;
    floatx4 z4 = {0.f, 0.f, 0.f, 0.f};

    for (int pp = 0; pp < 8; ++pp) {
        int n = nbase + pp;
        int id = knn[n * 16 + r16];
        float f0 = 0.f, f1 = 0.f, f2 = 0.f, f3 = 0.f, f4 = 0.f, f5 = 0.f, f6 = 0.f, f7 = 0.f;
        if (q == 0) {
            f0 = xyz[(size_t)id * 3 + 0] - xyz[(size_t)n * 3 + 0];
            f1 = xyz[(size_t)id * 3 + 1] - xyz[(size_t)n * 3 + 1];
            f2 = xyz[(size_t)id * 3 + 2] - xyz[(size_t)n * 3 + 2];
            dxyz_out[(size_t)n * 48 + r16 * 3 + 0] = f0;
            dxyz_out[(size_t)n * 48 + r16 * 3 + 1] = f1;
            dxyz_out[(size_t)n * 48 + r16 * 3 + 2] = f2;
            f3 = x[(size_t)id * 7 + 0]; f4 = x[(size_t)id * 7 + 1];
            f5 = x[(size_t)id * 7 + 2]; f6 = x[(size_t)id * 7 + 3];
            f7 = x[(size_t)id * 7 + 4];
        } else if (q == 1) {
            f0 = x[(size_t)id * 7 + 5]; f1 = x[(size_t)id * 7 + 6];
        }
        uint4 au = make_uint4(pack_bf2(f0, f1), pack_bf2(f2, f3),
                              pack_bf2(f4, f5), pack_bf2(f6, f7));
        short8 a1 = __builtin_bit_cast(short8, au);
        floatx4 c1 = __builtin_amdgcn_mfma_f32_16x16x32_bf16(a1, B1, z4, 0, 0, 0);
        #pragma unroll
        for (int rg = 0; rg < 4; ++rg)
            h1L[w][q * 4 + rg][r16] = f2bf(gelu_f(c1[rg] + b1r));

        short8 a2 = {0, 0, 0, 0, 0, 0, 0, 0};
        if (q < 2) a2 = *(const short8*)&h1L[w][r16][q * 8];
        #pragma unroll
        for (int nt = 0; nt < 2; ++nt) {
            floatx4 c2 = __builtin_amdgcn_mfma_f32_16x16x32_bf16(a2, B2[nt], z4, 0, 0, 0);
            float br = nt ? b2r1 : b2r0;
            #pragma unroll
            for (int rg = 0; rg < 4; ++rg)
                h2L[w][q * 4 + rg][nt * 16 + r16] = f2bf(gelu_f(c2[rg] + br));
        }

        short8 a3 = *(const short8*)&h2L[w][r16][q * 8];
        float keep0 = 0.f, keep1 = 0.f;
        #pragma unroll
        for (int tt = 0; tt < 8; ++tt) {
            floatx4 c3 = __builtin_amdgcn_mfma_f32_16x16x32_bf16(a3, B3[tt], z4, 0, 0, 0);
            float mx = fmaxf(fmaxf(c3.x, c3.y), fmaxf(c3.z, c3.w));
            mx = fmaxf(mx, __shfl_xor(mx, 16));
            mx = fmaxf(mx, __shfl_xor(mx, 32));
            if (tt == q)     keep0 = mx;
            if (tt == q + 4) keep1 = mx;
        }
        feat[(size_t)n * 128 + l]      = keep0 * bg0 + bb0;
        feat[(size_t)n * 128 + l + 64] = keep1 * bg1 + bb1;
    }
}

// ---------------------------------------------------------------------------
// Residual MLP via MFMA. Optional fused gpe pre-pass, optional fused xp-proj
// tail, optional fused postproj tail (BN + 128->256 GEMM to out).
// ---------------------------------------------------------------------------
__global__ __launch_bounds__(256, 2) void mlp_mfma(
    float* __restrict__ feat,
    const unsigned short* __restrict__ P1, const float* __restrict__ b1,
    const unsigned short* __restrict__ P2,
    const float* __restrict__ g, const float* __restrict__ b,
    const unsigned short* __restrict__ P_gpe, const float* __restrict__ g_pos,
    const unsigned short* __restrict__ P_proj, unsigned short* __restrict__ xpb,
    const float* __restrict__ ppg, const float* __restrict__ ppb,
    const unsigned short* __restrict__ P_out, float* __restrict__ outp)
{
    int t = threadIdx.x, w = t >> 6, l = t & 63;
    int q = l >> 4, r16 = l & 15;
    __shared__ __align__(16) unsigned short aS[16][136];
    __shared__ __align__(16) unsigned short hS[16][264];
    __shared__ __align__(16) float fS[16][132];

    const short8* B1 = (const short8*)P1;
    const short8* B2 = (const short8*)P2;
    short8 b1f[4][4];
    #pragma unroll
    for (int nt = 0; nt < 4; ++nt)
        #pragma unroll
        for (int ch = 0; ch < 4; ++ch)
            b1f[nt][ch] = B1[((w * 4 + nt) * 4 + ch) * 64 + l];
    short8 b2f[2][8];
    #pragma unroll
    for (int nt = 0; nt < 2; ++nt)
        #pragma unroll
        for (int ch = 0; ch < 8; ++ch)
            b2f[nt][ch] = B2[((w * 2 + nt) * 8 + ch) * 64 + l];
    float bb1[4];
    #pragma unroll
    for (int nt = 0; nt < 4; ++nt) bb1[nt] = b1[w * 64 + nt * 16 + r16];
    float gg[2], bb[2];
    float ppgv[2] = {0.f, 0.f}, ppbv[2] = {0.f, 0.f};
    #pragma unroll
    for (int nt = 0; nt < 2; ++nt) {
        int c = w * 32 + nt * 16 + r16;
        gg[nt] = g[c] * BN_RSQ; bb[nt] = b[c];
        if (outp) { ppgv[nt] = ppg[c] * BN_RSQ; ppbv[nt] = ppb[c]; }
    }
    floatx4 z4 = {0.f, 0.f, 0.f, 0.f};

    for (int itc = 0; itc < 4; ++itc) {
        int n0 = blockIdx.x * 64 + itc * 16;
        {
            int row = t >> 4, c8 = (t & 15) * 8;
            float4 fa = *(const float4*)&feat[(size_t)(n0 + row) * 128 + c8];
            float4 fb4 = *(const float4*)&feat[(size_t)(n0 + row) * 128 + c8 + 4];
            *(float4*)&fS[row][c8] = fa;
            *(float4*)&fS[row][c8 + 4] = fb4;
            if (!P_gpe) {
                *(uint4*)&aS[row][c8] = make_uint4(
                    pack_bf2(fa.x, fa.y), pack_bf2(fa.z, fa.w),
                    pack_bf2(fb4.x, fb4.y), pack_bf2(fb4.z, fb4.w));
            }
        }
        __syncthreads();

        if (P_gpe) {
            const short8* Bg = (const short8*)P_gpe;
            floatx4 cg[2] = {z4, z4};
            #pragma unroll
            for (int ch = 0; ch < 2; ++ch) {
                const float* gp = &g_pos[(size_t)(n0 + r16) * 64 + ch * 32 + q * 8];
                float4 ga = *(const float4*)gp;
                float4 gb4 = *(const float4*)(gp + 4);
                uint4 au = make_uint4(pack_bf2(ga.x, ga.y), pack_bf2(ga.z, ga.w),
                                      pack_bf2(gb4.x, gb4.y), pack_bf2(gb4.z, gb4.w));
                short8 ag = __builtin_bit_cast(short8, au);
                #pragma unroll
                for (int nt = 0; nt < 2; ++nt)
                    cg[nt] = __builtin_amdgcn_mfma_f32_16x16x32_bf16(ag, Bg[((2 * w + nt) * 2 + ch) * 64 + l], cg[nt], 0, 0, 0);
            }
            #pragma unroll
            for (int nt = 0; nt < 2; ++nt) {
                int c = (2 * w + nt) * 16 + r16;
                #pragma unroll
                for (int rg = 0; rg < 4; ++rg) {
                    int row = q * 4 + rg;
                    float v = fS[row][c] + cg[nt][rg];
                    fS[row][c] = v;
                    aS[row][c] = f2bf(v);
                }
            }
            __syncthreads();
        }

        floatx4 acc1[4];
        #pragma unroll
        for (int nt = 0; nt < 4; ++nt) acc1[nt] = z4;
        #pragma unroll
        for (int ch = 0; ch < 4; ++ch) {
            short8 af = *(const short8*)&aS[r16][ch * 32 + q * 8];
            #pragma unroll
            for (int nt = 0; nt < 4; ++nt)
                acc1[nt] = __builtin_amdgcn_mfma_f32_16x16x32_bf16(af, b1f[nt][ch], acc1[nt], 0, 0, 0);
        }
        #pragma unroll
        for (int nt = 0; nt < 4; ++nt) {
            int c = w * 64 + nt * 16 + r16;
            #pragma unroll
            for (int rg = 0; rg < 4; ++rg)
                hS[q * 4 + rg][c] = f2bf(gelu_f(acc1[nt][rg] + bb1[nt]));
        }
        __syncthreads();

        floatx4 acc2[2];
        #pragma unroll
        for (int nt = 0; nt < 2; ++nt) acc2[nt] = z4;
        #pragma unroll
        for (int ch = 0; ch < 8; ++ch) {
            short8 af = *(const short8*)&hS[r16][ch * 32 + q * 8];
            #pragma unroll
            for (int nt = 0; nt < 2; ++nt)
                acc2[nt] = __builtin_amdgcn_mfma_f32_16x16x32_bf16(af, b2f[nt][ch], acc2[nt], 0, 0, 0);
        }
        #pragma unroll
        for (int nt = 0; nt < 2; ++nt) {
            int c = w * 32 + nt * 16 + r16;
            #pragma unroll
            for (int rg = 0; rg < 4; ++rg) {
                int row = q * 4 + rg;
                float v = fS[row][c] + acc2[nt][rg] * gg[nt] + bb[nt];
                feat[(size_t)(n0 + row) * 128 + c] = v;
                if (P_proj) aS[row][c] = f2bf(v);
                if (outp)   aS[row][c] = f2bf(v * ppgv[nt] + ppbv[nt]);
            }
        }
        if (P_proj) {
            __syncthreads();
            const short8* Bp = (const short8*)P_proj;
            #pragma unroll
            for (int nt = 0; nt < 2; ++nt) {
                int tg = w * 2 + nt;
                floatx4 ap = z4;
                #pragma unroll
                for (int ch = 0; ch < 4; ++ch) {
                    short8 af = *(const short8*)&aS[r16][ch * 32 + q * 8];
                    ap = __builtin_amdgcn_mfma_f32_16x16x32_bf16(af, Bp[(tg * 4 + ch) * 64 + l], ap, 0, 0, 0);
                }
                #pragma unroll
                for (int rg = 0; rg < 4; ++rg)
                    xpb[(size_t)(n0 + q * 4 + rg) * 128 + tg * 16 + r16] = f2bf(ap[rg]);
            }
        }
        if (outp) {
            __syncthreads();
            const short8* Bo = (const short8*)P_out;
            #pragma unroll
            for (int tt = 0; tt < 4; ++tt) {
                floatx4 ao = z4;
                #pragma unroll
                for (int ch = 0; ch < 4; ++ch) {
                    short8 af = *(const short8*)&aS[r16][ch * 32 + q * 8];
                    ao = __builtin_amdgcn_mfma_f32_16x16x32_bf16(af, Bo[((w * 4 + tt) * 4 + ch) * 64 + l], ao, 0, 0, 0);
                }
                #pragma unroll
                for (int rg = 0; rg < 4; ++rg)
                    outp[(size_t)(n0 + q * 4 + rg) * 256 + (w * 4 + tt) * 16 + r16] = ao[rg];
            }
        }
        __syncthreads();
    }
}

// ---------------------------------------------------------------------------
// xp = feat @ proj (128->128), bf16 output (depths 1,3).
// ---------------------------------------------------------------------------
__global__ __launch_bounds__(256) void linear_mfma(
    const float* __restrict__ feat, const unsigned short* __restrict__ P,
    unsigned short* __restrict__ xp)
{
    int t = threadIdx.x, w = t >> 6, l = t & 63;
    int q = l >> 4, r16 = l & 15;
    __shared__ __align__(16) unsigned short aS[16][136];
    const short8* B = (const short8*)P;
    short8 bf[2][4];
    #pragma unroll
    for (int nt = 0; nt < 2; ++nt)
        #pragma unroll
        for (int ch = 0; ch < 4; ++ch)
            bf[nt][ch] = B[((w * 2 + nt) * 4 + ch) * 64 + l];
    floatx4 z4 = {0.f, 0.f, 0.f, 0.f};

    for (int itc = 0; itc < 4; ++itc) {
        int n0 = blockIdx.x * 64 + itc * 16;
        {
            int row = t >> 4, c8 = (t & 15) * 8;
            float4 fa = *(const float4*)&feat[(size_t)(n0 + row) * 128 + c8];
            float4 fb4 = *(const float4*)&feat[(size_t)(n0 + row) * 128 + c8 + 4];
            *(uint4*)&aS[row][c8] = make_uint4(
                pack_bf2(fa.x, fa.y), pack_bf2(fa.z, fa.w),
                pack_bf2(fb4.x, fb4.y), pack_bf2(fb4.z, fb4.w));
        }
        __syncthreads();
        floatx4 acc[2];
        #pragma unroll
        for (int nt = 0; nt < 2; ++nt) acc[nt] = z4;
        #pragma unroll
        for (int ch = 0; ch < 4; ++ch) {
            short8 af = *(const short8*)&aS[r16][ch * 32 + q * 8];
            #pragma unroll
            for (int nt = 0; nt < 2; ++nt)
                acc[nt] = __builtin_amdgcn_mfma_f32_16x16x32_bf16(af, bf[nt][ch], acc[nt], 0, 0, 0);
        }
        #pragma unroll
        for (int nt = 0; nt < 2; ++nt) {
            int c = w * 32 + nt * 16 + r16;
            #pragma unroll
            for (int rg = 0; rg < 4; ++rg)
                xp[(size_t)(n0 + q * 4 + rg) * 128 + c] = f2bf(acc[nt][rg]);
        }
        __syncthreads();
    }
}

// ---------------------------------------------------------------------------
// LFA: EXACT R4 lfa_mfma3 (measured 70.5 us/dispatch, VGPR 120, no spill).
// Do not modify this kernel without an A/B round: R5 (VGPR cap) and R6
// (poly-gelu + pack + LDS union) both regressed it.
// ---------------------------------------------------------------------------
__global__ __launch_bounds__(256, 2) void lfa_mfma3(
    float* __restrict__ feat, const unsigned short* __restrict__ xpb,
    const float* __restrict__ dxyz, const int* __restrict__ knn,
    const float* __restrict__ w1, const float* __restrict__ b1,
    const unsigned short* __restrict__ P_w3a, const float* __restrict__ Weff,
    const float* __restrict__ cbias, const unsigned short* __restrict__ P_w3b,
    const float* __restrict__ b3b,
    const float* __restrict__ lg, const float* __restrict__ lb)
{
    int w = threadIdx.x >> 6, l = threadIdx.x & 63;
    int q = l >> 4, r16 = l & 15;

    __shared__ __align__(16) float dxS[4][8][64];
    __shared__ __align__(16) unsigned short plA[4][16][72];
    __shared__ __align__(16) unsigned short tvS[4][8][132];
    __shared__ __align__(16) unsigned short gS[4][16][136];
    __shared__ int idS[4][128];

    int nbase = blockIdx.x * 32 + w * 8;

    #pragma unroll
    for (int i = 0; i < 2; ++i)
        idS[w][i * 64 + l] = knn[(size_t)nbase * 16 + i * 64 + l];
    #pragma unroll
    for (int i = 0; i < 6; ++i) {
        int gI = i * 64 + l;                 // 0..383
        int p = gI / 48, rr = gI % 48;
        int k = rr / 3, d = rr - k * 3;
        dxS[w][p][k * 4 + d] = dxyz[(size_t)nbase * 48 + gI];
    }

    short8 bfr[8][4];
    {
        const short8* bp = (const short8*)P_w3b;
        #pragma unroll
        for (int tt = 0; tt < 8; ++tt)
            #pragma unroll
            for (int ch = 0; ch < 4; ++ch)
                bfr[tt][ch] = bp[(tt * 4 + ch) * 64 + l];
    }
    int c0 = 2 * l;
    float2 we0 = *(const float2*)&Weff[c0];
    float2 we1 = *(const float2*)&Weff[128 + c0];
    float2 we2 = *(const float2*)&Weff[256 + c0];
    float w1r0 = w1[l], w1r1 = w1[64 + l], w1r2 = w1[128 + l], b1l = b1[l];
    float b3b0 = b3b[l], b3b1 = b3b[l + 64];
    float lg0 = lg[l] * BN_RSQ, lg1 = lg[l + 64] * BN_RSQ;
    float lb0 = lb[l], lb1 = lb[l + 64];
    floatx4 z4 = {0.f, 0.f, 0.f, 0.f};

    // p_local for 8 points (lane l owns hidden dim l)
    for (int p = 0; p < 8; ++p) {
        float m = -1e30f;
        #pragma unroll
        for (int k = 0; k < 16; ++k) {
            float4 d4 = *(const float4*)&dxS[w][p][k * 4];
            m = fmaxf(m, b1l + d4.x * w1r0 + d4.y * w1r1 + d4.z * w1r2);
        }
        plA[w][p][l] = f2bf_lfa(m);
    }

    // tv = cbias + pl @ w3a_bot : rows 8-15 garbage, discarded via q<2
    {
        floatx4 tacc[8];
        #pragma unroll
        for (int tt = 0; tt < 8; ++tt) tacc[tt] = z4;
        const short8* bpA = (const short8*)P_w3a;
        #pragma unroll
        for (int ch = 0; ch < 2; ++ch) {
            short8 af = *(const short8*)&plA[w][r16][ch * 32 + q * 8];
            #pragma unroll
            for (int tt = 0; tt < 8; ++tt)
                tacc[tt] = __builtin_amdgcn_mfma_f32_16x16x32_bf16(af, bpA[(tt * 2 + ch) * 64 + l], tacc[tt], 0, 0, 0);
        }
        if (q < 2) {
            #pragma unroll
            for (int tt = 0; tt < 8; ++tt) {
                float cb = cbias[tt * 16 + r16];
                #pragma unroll
                for (int rg = 0; rg < 4; ++rg)
                    tvS[w][q * 4 + rg][tt * 16 + r16] = f2bf_lfa(tacc[tt][rg] + cb);
            }
        }
    }

    for (int pp = 0; pp < 8; ++pp) {
        int n = nbase + pp;
        unsigned tvp = *(const unsigned*)&tvS[w][pp][c0];
        float tv0 = bf2f(tvp & 0xffffu), tv1 = bf2f(tvp >> 16);
        #pragma unroll
        for (int k = 0; k < 16; ++k) {
            float4 d4 = *(const float4*)&dxS[w][pp][k * 4];
            float s0 = tv0 + d4.x * we0.x + d4.y * we1.x + d4.z * we2.x;
            float s1 = tv1 + d4.x * we0.y + d4.y * we1.y + d4.z * we2.y;
            unsigned gw = (unsigned)f2bf_lfa(gelu_lfa(s0)) | ((unsigned)f2bf_lfa(gelu_lfa(s1)) << 16);
            *(unsigned*)&gS[w][k][c0] = gw;
        }

        floatx4 acc[8];
        #pragma unroll
        for (int tt = 0; tt < 8; ++tt) acc[tt] = z4;
        #pragma unroll
        for (int ch = 0; ch < 4; ++ch) {
            short8 af = *(const short8*)&gS[w][r16][ch * 32 + q * 8];
            #pragma unroll
            for (int tt = 0; tt < 8; ++tt)
                acc[tt] = __builtin_amdgcn_mfma_f32_16x16x32_bf16(af, bfr[tt][ch], acc[tt], 0, 0, 0);
        }

        const int* idp = &idS[w][pp * 16];
        int i0 = idp[q * 4 + 0], i1 = idp[q * 4 + 1];
        int i2 = idp[q * 4 + 2], i3 = idp[q * 4 + 3];
        float keep0 = 0.f, keep1 = 0.f;
        #pragma unroll
        for (int tt = 0; tt < 8; ++tt) {
            int cb = tt * 16 + r16;
            float v0 = acc[tt].x + bf2f(xpb[(size_t)i0 * 128 + cb]);
            float v1 = acc[tt].y + bf2f(xpb[(size_t)i1 * 128 + cb]);
            float v2 = acc[tt].z + bf2f(xpb[(size_t)i2 * 128 + cb]);
            float v3 = acc[tt].w + bf2f(xpb[(size_t)i3 * 128 + cb]);
            float mx = fmaxf(fmaxf(v0, v1), fmaxf(v2, v3));
            mx = fmaxf(mx, __shfl_xor(mx, 16));
            mx = fmaxf(mx, __shfl_xor(mx, 32));
            if (tt == q)     keep0 = mx;
            if (tt == q + 4) keep1 = mx;
        }
        size_t base = (size_t)n * 128;
        float x0 = bf2f(xpb[base + l]), x1 = bf2f(xpb[base + l + 64]);
        feat[base + l]      += (keep0 + b3b0 - x0) * lg0 + lb0;
        feat[base + l + 64] += (keep1 + b3b1 - x1) * lg1 + lb1;
    }
}

// ---------------------------------------------------------------------------
extern "C" void kernel_launch(void* const* d_in, const int* in_sizes, int n_in,
                              void* d_out, int out_size, void* d_ws, size_t ws_size,
                              hipStream_t stream) {
    const float* x       = (const float*)d_in[0];
    const float* xyz     = (const float*)d_in[1];
    const float* g_pos   = (const float*)d_in[2];
    const float* ne_w1   = (const float*)d_in[3];
    const float* ne_g1   = (const float*)d_in[4];
    const float* ne_b1   = (const float*)d_in[5];
    const float* ne_w2   = (const float*)d_in[6];
    const float* ne_g2   = (const float*)d_in[7];
    const float* ne_b2   = (const float*)d_in[8];
    const float* ne_w3   = (const float*)d_in[9];
    const float* nbr_g   = (const float*)d_in[10];
    const float* nbr_b   = (const float*)d_in[11];
    const float* gpe_w   = (const float*)d_in[12];
    const float* bm_w1   = (const float*)d_in[13];
    const float* bm_b1   = (const float*)d_in[14];
    const float* bm_w2   = (const float*)d_in[15];
    const float* bm_g    = (const float*)d_in[16];
    const float* bm_b    = (const float*)d_in[17];
    const float* lfa_proj = (const float*)d_in[18];
    const float* lfa_g   = (const float*)d_in[19];
    const float* lfa_b   = (const float*)d_in[20];
    const float* nca_w1  = (const float*)d_in[21];
    const float* nca_b1  = (const float*)d_in[22];
    const float* nca_w2  = (const float*)d_in[23];
    const float* nca_b2  = (const float*)d_in[24];
    const float* nca_w3a = (const float*)d_in[25];
    const float* nca_b3a = (const float*)d_in[26];
    const float* nca_w3b = (const float*)d_in[27];
    const float* nca_b3b = (const float*)d_in[28];
    const float* m_w1    = (const float*)d_in[29];
    const float* m_b1    = (const float*)d_in[30];
    const float* m_w2    = (const float*)d_in[31];
    const float* m_g     = (const float*)d_in[32];
    const float* m_b     = (const float*)d_in[33];
    const float* pp_g    = (const float*)d_in[34];
    const float* pp_b    = (const float*)d_in[35];
    const float* pp_w    = (const float*)d_in[36];
    const int*   knn     = (const int*)d_in[37];

    float* ws    = (float*)d_ws;
    float* dxyz  = ws;                                   // N*48
    float* feat  = dxyz + (size_t)NPTS * 48;             // N*128
    float* Weff  = feat + (size_t)NPTS * 128;            // 1536
    float* cbias = Weff + 1536;                          // 512
    unsigned short* xpb    = (unsigned short*)(cbias + 512);    // N*128
    unsigned short* P_bm1  = xpb + (size_t)NPTS * 128;   // 32768
    unsigned short* P_bm2  = P_bm1 + 32768;              // 32768
    unsigned short* P_m1   = P_bm2 + 32768;              // 65536
    unsigned short* P_m2   = P_m1 + 65536;               // 65536
    unsigned short* P_proj = P_m2 + 65536;               // 65536
    unsigned short* P_pp   = P_proj + 65536;             // 32768
    unsigned short* P_w3a  = P_pp + 32768;               // 32768
    unsigned short* P_w3b  = P_w3a + 32768;              // 65536
    unsigned short* P_ne3  = P_w3b + 65536;              // 4096
    unsigned short* P_gpe  = P_ne3 + 4096;               // 8192
    unsigned short* P_ne1  = P_gpe + 8192;               // 512
    unsigned short* P_ne2  = P_ne1 + 512;                // 1024
    float* out = (float*)d_out;

    hipLaunchKernelGGL(precompute_kernel, dim3(4), dim3(128), 0, stream,
                       nca_w1, nca_b1, nca_w2, nca_b2, nca_w3a, nca_b3a, Weff, cbias);
    hipLaunchKernelGGL(pack_all, dim3(795), dim3(64), 0, stream,
                       bm_w1, bm_w2, m_w1, m_w2, lfa_proj, pp_w, nca_w3a, nca_w3b,
                       ne_w3, gpe_w, ne_w1, ne_g1, ne_w2, ne_g2,
                       P_bm1, P_bm2, P_m1, P_m2, P_proj, P_pp, P_w3a, P_w3b,
                       P_ne3, P_gpe, P_ne1, P_ne2);
    hipLaunchKernelGGL(nbr_embed_v2, dim3(1024), dim3(256), 0, stream,
                       x, xyz, knn, ne_b1, ne_b2, P_ne1, P_ne2, P_ne3,
                       nbr_g, nbr_b, dxyz, feat);
    // bm MLP with fused gpe add and fused proj_0
    hipLaunchKernelGGL(mlp_mfma, dim3(512), dim3(256), 0, stream,
                       feat, P_bm1, bm_b1, P_bm2, bm_g, bm_b,
                       P_gpe, g_pos, P_proj, xpb,
                       (const float*)nullptr, (const float*)nullptr,
                       (const unsigned short*)nullptr, (float*)nullptr);
    for (int i = 0; i < 4; ++i) {
        hipLaunchKernelGGL(lfa_mfma3, dim3(1024), dim3(256), 0, stream,
                           feat, xpb, dxyz, knn,
                           nca_w1 + (size_t)i * 192, nca_b1 + (size_t)i * 64,
                           P_w3a + (size_t)i * 8192,
                           Weff + (size_t)i * 384, cbias + (size_t)i * 128,
                           P_w3b + (size_t)i * 16384,
                           nca_b3b + (size_t)i * 128,
                           lfa_g + (size_t)i * 128, lfa_b + (size_t)i * 128);
        if (i == 0 || i == 2) {
            hipLaunchKernelGGL(linear_mfma, dim3(512), dim3(256), 0, stream,
                               feat, P_proj + (size_t)(i + 1) * 16384, xpb);
        } else if (i == 1) {
            // interleaved MLP 0 with fused proj_2
            hipLaunchKernelGGL(mlp_mfma, dim3(512), dim3(256), 0, stream,
                               feat, P_m1, m_b1, P_m2, m_g, m_b,
                               (const unsigned short*)nullptr, (const float*)nullptr,
                               P_proj + (size_t)2 * 16384, xpb,
                               (const float*)nullptr, (const float*)nullptr,
                               (const unsigned short*)nullptr, (float*)nullptr);
        } else {
            // final interleaved MLP with fused postproj (BN + 128->256 GEMM)
            hipLaunchKernelGGL(mlp_mfma, dim3(512), dim3(256), 0, stream,
                               feat, P_m1 + 32768, m_b1 + 256,
                               P_m2 + 32768, m_g + 128, m_b + 128,
                               (const unsigned short*)nullptr, (const float*)nullptr,
                               (const unsigned short*)nullptr, xpb,
                               pp_g, pp_b, P_pp, out);
        }
    }
}

// Round 8
// 509.008 us; speedup vs baseline: 1.9611x; 1.0019x over previous
//
#include <hip/hip_runtime.h>
#include <math.h>

#define NPTS 32768
#define BN_RSQ 0.9999950000374997f

typedef __attribute__((ext_vector_type(8))) short short8;
typedef __attribute__((ext_vector_type(4))) float floatx4;

// Polynomial GELU (used in non-lfa kernels; measured neutral there).
__device__ __forceinline__ float gelu_f(float v) {
    float t = fminf(fmaxf(v, -3.0f), 3.0f);
    float t2 = t * t;
    float p = fmaf(t2, fmaf(t2, fmaf(t2, -2.83231e-4f, 6.51008e-3f), -6.12871e-2f), 0.396958f);
    float phi = fmaf(t, p, 0.5f);
    phi = fminf(fmaxf(phi, 0.0f), 1.0f);
    return v * phi;
}
__device__ __forceinline__ unsigned short f2bf(float f) {
    unsigned u = __float_as_uint(f) + 0x8000u;
    return (unsigned short)(u >> 16);
}
__device__ __forceinline__ unsigned pack_bf2(float lo, float hi) {
    unsigned ul = __float_as_uint(lo) + 0x8000u;
    unsigned uh = __float_as_uint(hi) + 0x8000u;
    return __builtin_amdgcn_perm(uh, ul, 0x07060302u);
}
__device__ __forceinline__ float bf2f(unsigned u) {
    return __uint_as_float(u << 16);
}

// --- lfa-local helpers: EXACT R4 versions (do not share with other kernels) ---
__device__ __forceinline__ float gelu_lfa(float v) {
    float c = v * v;
    float z = v * (1.5957691f + 0.07135685f * c);
    float s = __builtin_amdgcn_rcpf(1.0f + __expf(-z));
    return v * s;
}
__device__ __forceinline__ unsigned short f2bf_lfa(float f) {
    unsigned u = __float_as_uint(f);
    u += 0x7fffu + ((u >> 16) & 1u);
    return (unsigned short)(u >> 16);
}

// ---------------------------------------------------------------------------
// Folded matrices per depth: Weff[i] = w1@w2@w3a_top (3x128),
// cbias[i] = (b1@w2 + b2)@w3a_top + b3a (128)
// ---------------------------------------------------------------------------
__global__ __launch_bounds__(128) void precompute_kernel(
    const float* __restrict__ nca_w1, const float* __restrict__ nca_b1,
    const float* __restrict__ nca_w2, const float* __restrict__ nca_b2,
    const float* __restrict__ nca_w3a, const float* __restrict__ nca_b3a,
    float* __restrict__ Weff, float* __restrict__ cbias)
{
    int i = blockIdx.x;
    int t = threadIdx.x;
    const float* w1 = nca_w1 + i * 3 * 64;
    const float* b1 = nca_b1 + i * 64;
    const float* w2 = nca_w2 + i * 64 * 64;
    const float* b2 = nca_b2 + i * 64;
    const float* w3a = nca_w3a + i * 128 * 128;
    const float* b3a = nca_b3a + i * 128;

    __shared__ float u[3][64];
    __shared__ float v[64];
    if (t < 64) {
        for (int r = 0; r < 3; ++r) {
            float s = 0.f;
            for (int m = 0; m < 64; ++m) s += w1[r * 64 + m] * w2[m * 64 + t];
            u[r][t] = s;
        }
        float s = 0.f;
        for (int m = 0; m < 64; ++m) s += b1[m] * w2[m * 64 + t];
        v[t] = s + b2[t];
    }
    __syncthreads();
    for (int r = 0; r < 3; ++r) {
        float s = 0.f;
        for (int m = 0; m < 64; ++m) s += u[r][m] * w3a[m * 128 + t];
        Weff[i * 384 + r * 128 + t] = s;
    }
    {
        float s = 0.f;
        for (int m = 0; m < 64; ++m) s += v[m] * w3a[m * 128 + t];
        cbias[i * 128 + t] = s + b3a[t];
    }
}

// ---------------------------------------------------------------------------
// Generic B-fragment packer (bf16 MFMA B layout), zero-pad beyond Kr,
// optional per-column gamma fold.
// ---------------------------------------------------------------------------
__global__ __launch_bounds__(64) void pack_all(
    const float* __restrict__ bm_w1, const float* __restrict__ bm_w2,
    const float* __restrict__ m_w1, const float* __restrict__ m_w2,
    const float* __restrict__ lfa_proj, const float* __restrict__ pp_w,
    const float* __restrict__ nca_w3a, const float* __restrict__ nca_w3b,
    const float* __restrict__ ne_w3, const float* __restrict__ gpe_w,
    const float* __restrict__ ne_w1, const float* __restrict__ ne_g1,
    const float* __restrict__ ne_w2, const float* __restrict__ ne_g2,
    unsigned short* __restrict__ P_bm1, unsigned short* __restrict__ P_bm2,
    unsigned short* __restrict__ P_m1, unsigned short* __restrict__ P_m2,
    unsigned short* __restrict__ P_proj, unsigned short* __restrict__ P_pp,
    unsigned short* __restrict__ P_w3a, unsigned short* __restrict__ P_w3b,
    unsigned short* __restrict__ P_ne3, unsigned short* __restrict__ P_gpe,
    unsigned short* __restrict__ P_ne1, unsigned short* __restrict__ P_ne2)
{
    int b = blockIdx.x, l = threadIdx.x;
    const float* src; unsigned short* dst; int K, C, fb; int Kr = 0;
    const float* fold = nullptr;
    if (b < 64)       { src = bm_w1; dst = P_bm1; K = 128; C = 256; fb = b; }
    else if (b < 128) { src = bm_w2; dst = P_bm2; K = 256; C = 128; fb = b - 64; }
    else if (b < 256) { int i = (b - 128) >> 6; src = m_w1 + i * 32768; dst = P_m1 + i * 32768; K = 128; C = 256; fb = (b - 128) & 63; }
    else if (b < 384) { int i = (b - 256) >> 6; src = m_w2 + i * 32768; dst = P_m2 + i * 32768; K = 256; C = 128; fb = (b - 256) & 63; }
    else if (b < 512) { int i = (b - 384) >> 5; src = lfa_proj + i * 16384; dst = P_proj + i * 16384; K = 128; C = 128; fb = (b - 384) & 31; }
    else if (b < 576) { src = pp_w; dst = P_pp; K = 128; C = 256; fb = b - 512; }
    else if (b < 640) { int i = (b - 576) >> 4; src = nca_w3a + i * 16384 + 64 * 128; dst = P_w3a + i * 8192; K = 64; C = 128; fb = (b - 576) & 15; }
    else if (b < 768) { int i = (b - 640) >> 5; src = nca_w3b + i * 16384; dst = P_w3b + i * 16384; K = 128; C = 128; fb = (b - 640) & 31; }
    else if (b < 776) { src = ne_w3; dst = P_ne3; K = 32; C = 128; fb = b - 768; }
    else if (b < 792) { src = gpe_w; dst = P_gpe; K = 64; C = 128; fb = b - 776; }
    else if (b == 792){ src = ne_w1; dst = P_ne1; K = 32; C = 16; fb = 0; Kr = 10; fold = ne_g1; }
    else              { src = ne_w2; dst = P_ne2; K = 32; C = 32; fb = b - 793; Kr = 16; fold = ne_g2; }
    if (Kr == 0) Kr = K;
    int Kc = K >> 5;
    int tile = fb / Kc, chunk = fb % Kc;
    unsigned short* o = dst + ((size_t)fb * 64 + l) * 8;
    #pragma unroll
    for (int j = 0; j < 8; ++j) {
        int kk = chunk * 32 + (l >> 4) * 8 + j;
        int nn = tile * 16 + (l & 15);
        float v = 0.f;
        if (kk < Kr) {
            v = src[kk * C + nn];
            if (fold) v *= fold[nn] * BN_RSQ;
        }
        o[j] = f2bf(v);
    }
}

// ---------------------------------------------------------------------------
// Neighbor embedding: 4 independent waves/block, zero barriers, all 3 layers
// MFMA. grid 1024 x 256, 8 points/wave.
// ---------------------------------------------------------------------------
__global__ __launch_bounds__(256) void nbr_embed_v2(
    const float* __restrict__ x, const float* __restrict__ xyz,
    const int* __restrict__ knn,
    const float* __restrict__ ne_b1, const float* __restrict__ ne_b2,
    const unsigned short* __restrict__ P_ne1, const unsigned short* __restrict__ P_ne2,
    const unsigned short* __restrict__ P_ne3,
    const float* __restrict__ nbr_g, const float* __restrict__ nbr_b,
    float* __restrict__ dxyz_out, float* __restrict__ feat)
{
    int t = threadIdx.x, w = t >> 6, l = t & 63, q = l >> 4, r16 = l & 15;
    __shared__ __align__(16) unsigned short h1L[4][16][24];
    __shared__ __align__(16) unsigned short h2L[4][16][40];

    short8 B1 = ((const short8*)P_ne1)[l];
    short8 B2[2], B3[8];
    B2[0] = ((const short8*)P_ne2)[l];
    B2[1] = ((const short8*)P_ne2)[64 + l];
    #pragma unroll
    for (int tt = 0; tt < 8; ++tt) B3[tt] = ((const short8*)P_ne3)[tt * 64 + l];
    float b1r = ne_b1[r16];
    float b2r0 = ne_b2[r16], b2r1 = ne_b2[16 + r16];
    float bg0 = nbr_g[l] * BN_RSQ, bb0 = nbr_b[l];
    float bg1 = nbr_g[l + 64] * BN_RSQ, bb1 = nbr_b[l + 64];
    int nbase = blockIdx.x * 32 + w * 8;
    floatx4 z4 = {0.f, 0.f, 0.f, 0.f};

    for (int pp = 0; pp < 8; ++pp) {
        int n = nbase + pp;
        int id = knn[n * 16 + r16];
        float f0 = 0.f, f1 = 0.f, f2 = 0.f, f3 = 0.f, f4 = 0.f, f5 = 0.f, f6 = 0.f, f7 = 0.f;
        if (q == 0) {
            f0 = xyz[(size_t)id * 3 + 0] - xyz[(size_t)n * 3 + 0];
            f1 = xyz[(size_t)id * 3 + 1] - xyz[(size_t)n * 3 + 1];
            f2 = xyz[(size_t)id * 3 + 2] - xyz[(size_t)n * 3 + 2];
            dxyz_out[(size_t)n * 48 + r16 * 3 + 0] = f0;
            dxyz_out[(size_t)n * 48 + r16 * 3 + 1] = f1;
            dxyz_out[(size_t)n * 48 + r16 * 3 + 2] = f2;
            f3 = x[(size_t)id * 7 + 0]; f4 = x[(size_t)id * 7 + 1];
            f5 = x[(size_t)id * 7 + 2]; f6 = x[(size_t)id * 7 + 3];
            f7 = x[(size_t)id * 7 + 4];
        } else if (q == 1) {
            f0 = x[(size_t)id * 7 + 5]; f1 = x[(size_t)id * 7 + 6];
        }
        uint4 au = make_uint4(pack_bf2(f0, f1), pack_bf2(f2, f3),
                              pack_bf2(f4, f5), pack_bf2(f6, f7));
        short8 a1 = __builtin_bit_cast(short8, au);
        floatx4 c1 = __builtin_amdgcn_mfma_f32_16x16x32_bf16(a1, B1, z4, 0, 0, 0);
        #pragma unroll
        for (int rg = 0; rg < 4; ++rg)
            h1L[w][q * 4 + rg][r16] = f2bf(gelu_f(c1[rg] + b1r));

        short8 a2 = {0, 0, 0, 0, 0, 0, 0, 0};
        if (q < 2) a2 = *(const short8*)&h1L[w][r16][q * 8];
        #pragma unroll
        for (int nt = 0; nt < 2; ++nt) {
            floatx4 c2 = __builtin_amdgcn_mfma_f32_16x16x32_bf16(a2, B2[nt], z4, 0, 0, 0);
            float br = nt ? b2r1 : b2r0;
            #pragma unroll
            for (int rg = 0; rg < 4; ++rg)
                h2L[w][q * 4 + rg][nt * 16 + r16] = f2bf(gelu_f(c2[rg] + br));
        }

        short8 a3 = *(const short8*)&h2L[w][r16][q * 8];
        float keep0 = 0.f, keep1 = 0.f;
        #pragma unroll
        for (int tt = 0; tt < 8; ++tt) {
            floatx4 c3 = __builtin_amdgcn_mfma_f32_16x16x32_bf16(a3, B3[tt], z4, 0, 0, 0);
            float mx = fmaxf(fmaxf(c3.x, c3.y), fmaxf(c3.z, c3.w));
            mx = fmaxf(mx, __shfl_xor(mx, 16));
            mx = fmaxf(mx, __shfl_xor(mx, 32));
            if (tt == q)     keep0 = mx;
            if (tt == q + 4) keep1 = mx;
        }
        feat[(size_t)n * 128 + l]      = keep0 * bg0 + bb0;
        feat[(size_t)n * 128 + l + 64] = keep1 * bg1 + bb1;
    }
}

// ---------------------------------------------------------------------------
// Residual MLP via MFMA. Optional fused gpe pre-pass, optional fused xp-proj
// tail, optional fused postproj tail (BN + 128->256 GEMM to out).
// ---------------------------------------------------------------------------
__global__ __launch_bounds__(256, 2) void mlp_mfma(
    float* __restrict__ feat,
    const unsigned short* __restrict__ P1, const float* __restrict__ b1,
    const unsigned short* __restrict__ P2,
    const float* __restrict__ g, const float* __restrict__ b,
    const unsigned short* __restrict__ P_gpe, const float* __restrict__ g_pos,
    const unsigned short* __restrict__ P_proj, unsigned short* __restrict__ xpb,
    const float* __restrict__ ppg, const float* __restrict__ ppb,
    const unsigned short* __restrict__ P_out, float* __restrict__ outp)
{
    int t = threadIdx.x, w = t >> 6, l = t & 63;
    int q = l >> 4, r16 = l & 15;
    __shared__ __align__(16) unsigned short aS[16][136];
    __shared__ __align__(16) unsigned short hS[16][264];
    __shared__ __align__(16) float fS[16][132];

    const short8* B1 = (const short8*)P1;
    const short8* B2 = (const short8*)P2;
    short8 b1f[4][4];
    #pragma unroll
    for (int nt = 0; nt < 4; ++nt)
        #pragma unroll
        for (int ch = 0; ch < 4; ++ch)
            b1f[nt][ch] = B1[((w * 4 + nt) * 4 + ch) * 64 + l];
    short8 b2f[2][8];
    #pragma unroll
    for (int nt = 0; nt < 2; ++nt)
        #pragma unroll
        for (int ch = 0; ch < 8; ++ch)
            b2f[nt][ch] = B2[((w * 2 + nt) * 8 + ch) * 64 + l];
    float bb1[4];
    #pragma unroll
    for (int nt = 0; nt < 4; ++nt) bb1[nt] = b1[w * 64 + nt * 16 + r16];
    float gg[2], bb[2];
    float ppgv[2] = {0.f, 0.f}, ppbv[2] = {0.f, 0.f};
    #pragma unroll
    for (int nt = 0; nt < 2; ++nt) {
        int c = w * 32 + nt * 16 + r16;
        gg[nt] = g[c] * BN_RSQ; bb[nt] = b[c];
        if (outp) { ppgv[nt] = ppg[c] * BN_RSQ; ppbv[nt] = ppb[c]; }
    }
    floatx4 z4 = {0.f, 0.f, 0.f, 0.f};

    for (int itc = 0; itc < 4; ++itc) {
        int n0 = blockIdx.x * 64 + itc * 16;
        {
            int row = t >> 4, c8 = (t & 15) * 8;
            float4 fa = *(const float4*)&feat[(size_t)(n0 + row) * 128 + c8];
            float4 fb4 = *(const float4*)&feat[(size_t)(n0 + row) * 128 + c8 + 4];
            *(float4*)&fS[row][c8] = fa;
            *(float4*)&fS[row][c8 + 4] = fb4;
            if (!P_gpe) {
                *(uint4*)&aS[row][c8] = make_uint4(
                    pack_bf2(fa.x, fa.y), pack_bf2(fa.z, fa.w),
                    pack_bf2(fb4.x, fb4.y), pack_bf2(fb4.z, fb4.w));
            }
        }
        __syncthreads();

        if (P_gpe) {
            const short8* Bg = (const short8*)P_gpe;
            floatx4 cg[2] = {z4, z4};
            #pragma unroll
            for (int ch = 0; ch < 2; ++ch) {
                const float* gp = &g_pos[(size_t)(n0 + r16) * 64 + ch * 32 + q * 8];
                float4 ga = *(const float4*)gp;
                float4 gb4 = *(const float4*)(gp + 4);
                uint4 au = make_uint4(pack_bf2(ga.x, ga.y), pack_bf2(ga.z, ga.w),
                                      pack_bf2(gb4.x, gb4.y), pack_bf2(gb4.z, gb4.w));
                short8 ag = __builtin_bit_cast(short8, au);
                #pragma unroll
                for (int nt = 0; nt < 2; ++nt)
                    cg[nt] = __builtin_amdgcn_mfma_f32_16x16x32_bf16(ag, Bg[((2 * w + nt) * 2 + ch) * 64 + l], cg[nt], 0, 0, 0);
            }
            #pragma unroll
            for (int nt = 0; nt < 2; ++nt) {
                int c = (2 * w + nt) * 16 + r16;
                #pragma unroll
                for (int rg = 0; rg < 4; ++rg) {
                    int row = q * 4 + rg;
                    float v = fS[row][c] + cg[nt][rg];
                    fS[row][c] = v;
                    aS[row][c] = f2bf(v);
                }
            }
            __syncthreads();
        }

        floatx4 acc1[4];
        #pragma unroll
        for (int nt = 0; nt < 4; ++nt) acc1[nt] = z4;
        #pragma unroll
        for (int ch = 0; ch < 4; ++ch) {
            short8 af = *(const short8*)&aS[r16][ch * 32 + q * 8];
            #pragma unroll
            for (int nt = 0; nt < 4; ++nt)
                acc1[nt] = __builtin_amdgcn_mfma_f32_16x16x32_bf16(af, b1f[nt][ch], acc1[nt], 0, 0, 0);
        }
        #pragma unroll
        for (int nt = 0; nt < 4; ++nt) {
            int c = w * 64 + nt * 16 + r16;
            #pragma unroll
            for (int rg = 0; rg < 4; ++rg)
                hS[q * 4 + rg][c] = f2bf(gelu_f(acc1[nt][rg] + bb1[nt]));
        }
        __syncthreads();

        floatx4 acc2[2];
        #pragma unroll
        for (int nt = 0; nt < 2; ++nt) acc2[nt] = z4;
        #pragma unroll
        for (int ch = 0; ch < 8; ++ch) {
            short8 af = *(const short8*)&hS[r16][ch * 32 + q * 8];
            #pragma unroll
            for (int nt = 0; nt < 2; ++nt)
                acc2[nt] = __builtin_amdgcn_mfma_f32_16x16x32_bf16(af, b2f[nt][ch], acc2[nt], 0, 0, 0);
        }
        #pragma unroll
        for (int nt = 0; nt < 2; ++nt) {
            int c = w * 32 + nt * 16 + r16;
            #pragma unroll
            for (int rg = 0; rg < 4; ++rg) {
                int row = q * 4 + rg;
                float v = fS[row][c] + acc2[nt][rg] * gg[nt] + bb[nt];
                feat[(size_t)(n0 + row) * 128 + c] = v;
                if (P_proj) aS[row][c] = f2bf(v);
                if (outp)   aS[row][c] = f2bf(v * ppgv[nt] + ppbv[nt]);
            }
        }
        if (P_proj) {
            __syncthreads();
            const short8* Bp = (const short8*)P_proj;
            #pragma unroll
            for (int nt = 0; nt < 2; ++nt) {
                int tg = w * 2 + nt;
                floatx4 ap = z4;
                #pragma unroll
                for (int ch = 0; ch < 4; ++ch) {
                    short8 af = *(const short8*)&aS[r16][ch * 32 + q * 8];
                    ap = __builtin_amdgcn_mfma_f32_16x16x32_bf16(af, Bp[(tg * 4 + ch) * 64 + l], ap, 0, 0, 0);
                }
                #pragma unroll
                for (int rg = 0; rg < 4; ++rg)
                    xpb[(size_t)(n0 + q * 4 + rg) * 128 + tg * 16 + r16] = f2bf(ap[rg]);
            }
        }
        if (outp) {
            __syncthreads();
            const short8* Bo = (const short8*)P_out;
            #pragma unroll
            for (int tt = 0; tt < 4; ++tt) {
                floatx4 ao = z4;
                #pragma unroll
                for (int ch = 0; ch < 4; ++ch) {
                    short8 af = *(const short8*)&aS[r16][ch * 32 + q * 8];
                    ao = __builtin_amdgcn_mfma_f32_16x16x32_bf16(af, Bo[((w * 4 + tt) * 4 + ch) * 64 + l], ao, 0, 0, 0);
                }
                #pragma unroll
                for (int rg = 0; rg < 4; ++rg)
                    outp[(size_t)(n0 + q * 4 + rg) * 256 + (w * 4 + tt) * 16 + r16] = ao[rg];
            }
        }
        __syncthreads();
    }
}

// ---------------------------------------------------------------------------
// xp = feat @ proj (128->128), bf16 output (depths 1,3).
// ---------------------------------------------------------------------------
__global__ __launch_bounds__(256) void linear_mfma(
    const float* __restrict__ feat, const unsigned short* __restrict__ P,
    unsigned short* __restrict__ xp)
{
    int t = threadIdx.x, w = t >> 6, l = t & 63;
    int q = l >> 4, r16 = l & 15;
    __shared__ __align__(16) unsigned short aS[16][136];
    const short8* B = (const short8*)P;
    short8 bf[2][4];
    #pragma unroll
    for (int nt = 0; nt < 2; ++nt)
        #pragma unroll
        for (int ch = 0; ch < 4; ++ch)
            bf[nt][ch] = B[((w * 2 + nt) * 4 + ch) * 64 + l];
    floatx4 z4 = {0.f, 0.f, 0.f, 0.f};

    for (int itc = 0; itc < 4; ++itc) {
        int n0 = blockIdx.x * 64 + itc * 16;
        {
            int row = t >> 4, c8 = (t & 15) * 8;
            float4 fa = *(const float4*)&feat[(size_t)(n0 + row) * 128 + c8];
            float4 fb4 = *(const float4*)&feat[(size_t)(n0 + row) * 128 + c8 + 4];
            *(uint4*)&aS[row][c8] = make_uint4(
                pack_bf2(fa.x, fa.y), pack_bf2(fa.z, fa.w),
                pack_bf2(fb4.x, fb4.y), pack_bf2(fb4.z, fb4.w));
        }
        __syncthreads();
        floatx4 acc[2];
        #pragma unroll
        for (int nt = 0; nt < 2; ++nt) acc[nt] = z4;
        #pragma unroll
        for (int ch = 0; ch < 4; ++ch) {
            short8 af = *(const short8*)&aS[r16][ch * 32 + q * 8];
            #pragma unroll
            for (int nt = 0; nt < 2; ++nt)
                acc[nt] = __builtin_amdgcn_mfma_f32_16x16x32_bf16(af, bf[nt][ch], acc[nt], 0, 0, 0);
        }
        #pragma unroll
        for (int nt = 0; nt < 2; ++nt) {
            int c = w * 32 + nt * 16 + r16;
            #pragma unroll
            for (int rg = 0; rg < 4; ++rg)
                xp[(size_t)(n0 + q * 4 + rg) * 128 + c] = f2bf(acc[nt][rg]);
        }
        __syncthreads();
    }
}

// ---------------------------------------------------------------------------
// LFA R8: R7/R4 kernel with ONE change — the dead-after-preamble plA buffer
// is folded into gS (rows 0..7 hold p_local during the preamble; the per-point
// loop later overwrites all 16 rows with GELU output). LDS 45568 -> ~36352 B
// => 4 blocks/CU, grid 1024 divides 256 CUs exactly. GELU/f2bf/launch_bounds
// unchanged (R5/R6 showed those changes regress this kernel).
// ---------------------------------------------------------------------------
__global__ __launch_bounds__(256, 2) void lfa_mfma3(
    float* __restrict__ feat, const unsigned short* __restrict__ xpb,
    const float* __restrict__ dxyz, const int* __restrict__ knn,
    const float* __restrict__ w1, const float* __restrict__ b1,
    const unsigned short* __restrict__ P_w3a, const float* __restrict__ Weff,
    const float* __restrict__ cbias, const unsigned short* __restrict__ P_w3b,
    const float* __restrict__ b3b,
    const float* __restrict__ lg, const float* __restrict__ lb)
{
    int w = threadIdx.x >> 6, l = threadIdx.x & 63;
    int q = l >> 4, r16 = l & 15;

    __shared__ __align__(16) float dxS[4][8][64];
    __shared__ __align__(16) unsigned short tvS[4][8][132];
    // gS phase A: p_local rows 0..7 (cols 0..63). Phase B: GELU(a) rows 0..15.
    // Same-wave sequential use; no cross-wave sharing.
    __shared__ __align__(16) unsigned short gS[4][16][136];
    __shared__ int idS[4][128];

    int nbase = blockIdx.x * 32 + w * 8;

    #pragma unroll
    for (int i = 0; i < 2; ++i)
        idS[w][i * 64 + l] = knn[(size_t)nbase * 16 + i * 64 + l];
    #pragma unroll
    for (int i = 0; i < 6; ++i) {
        int gI = i * 64 + l;                 // 0..383
        int p = gI / 48, rr = gI % 48;
        int k = rr / 3, d = rr - k * 3;
        dxS[w][p][k * 4 + d] = dxyz[(size_t)nbase * 48 + gI];
    }

    short8 bfr[8][4];
    {
        const short8* bp = (const short8*)P_w3b;
        #pragma unroll
        for (int tt = 0; tt < 8; ++tt)
            #pragma unroll
            for (int ch = 0; ch < 4; ++ch)
                bfr[tt][ch] = bp[(tt * 4 + ch) * 64 + l];
    }
    int c0 = 2 * l;
    float2 we0 = *(const float2*)&Weff[c0];
    float2 we1 = *(const float2*)&Weff[128 + c0];
    float2 we2 = *(const float2*)&Weff[256 + c0];
    float w1r0 = w1[l], w1r1 = w1[64 + l], w1r2 = w1[128 + l], b1l = b1[l];
    float b3b0 = b3b[l], b3b1 = b3b[l + 64];
    float lg0 = lg[l] * BN_RSQ, lg1 = lg[l + 64] * BN_RSQ;
    float lb0 = lb[l], lb1 = lb[l + 64];
    floatx4 z4 = {0.f, 0.f, 0.f, 0.f};

    // phase A: p_local for 8 points into gS rows 0..7 (lane l owns hidden dim l)
    for (int p = 0; p < 8; ++p) {
        float m = -1e30f;
        #pragma unroll
        for (int k = 0; k < 16; ++k) {
            float4 d4 = *(const float4*)&dxS[w][p][k * 4];
            m = fmaxf(m, b1l + d4.x * w1r0 + d4.y * w1r1 + d4.z * w1r2);
        }
        gS[w][p][l] = f2bf_lfa(m);
    }

    // tv = cbias + pl @ w3a_bot : rows 8-15 garbage, discarded via q<2
    {
        floatx4 tacc[8];
        #pragma unroll
        for (int tt = 0; tt < 8; ++tt) tacc[tt] = z4;
        const short8* bpA = (const short8*)P_w3a;
        #pragma unroll
        for (int ch = 0; ch < 2; ++ch) {
            short8 af = *(const short8*)&gS[w][r16][ch * 32 + q * 8];
            #pragma unroll
            for (int tt = 0; tt < 8; ++tt)
                tacc[tt] = __builtin_amdgcn_mfma_f32_16x16x32_bf16(af, bpA[(tt * 2 + ch) * 64 + l], tacc[tt], 0, 0, 0);
        }
        if (q < 2) {
            #pragma unroll
            for (int tt = 0; tt < 8; ++tt) {
                float cb = cbias[tt * 16 + r16];
                #pragma unroll
                for (int rg = 0; rg < 4; ++rg)
                    tvS[w][q * 4 + rg][tt * 16 + r16] = f2bf_lfa(tacc[tt][rg] + cb);
            }
        }
    }

    for (int pp = 0; pp < 8; ++pp) {
        int n = nbase + pp;
        unsigned tvp = *(const unsigned*)&tvS[w][pp][c0];
        float tv0 = bf2f(tvp & 0xffffu), tv1 = bf2f(tvp >> 16);
        #pragma unroll
        for (int k = 0; k < 16; ++k) {
            float4 d4 = *(const float4*)&dxS[w][pp][k * 4];
            float s0 = tv0 + d4.x * we0.x + d4.y * we1.x + d4.z * we2.x;
            float s1 = tv1 + d4.x * we0.y + d4.y * we1.y + d4.z * we2.y;
            unsigned gw = (unsigned)f2bf_lfa(gelu_lfa(s0)) | ((unsigned)f2bf_lfa(gelu_lfa(s1)) << 16);
            *(unsigned*)&gS[w][k][c0] = gw;
        }

        floatx4 acc[8];
        #pragma unroll
        for (int tt = 0; tt < 8; ++tt) acc[tt] = z4;
        #pragma unroll
        for (int ch = 0; ch < 4; ++ch) {
            short8 af = *(const short8*)&gS[w][r16][ch * 32 + q * 8];
            #pragma unroll
            for (int tt = 0; tt < 8; ++tt)
                acc[tt] = __builtin_amdgcn_mfma_f32_16x16x32_bf16(af, bfr[tt][ch], acc[tt], 0, 0, 0);
        }

        const int* idp = &idS[w][pp * 16];
        int i0 = idp[q * 4 + 0], i1 = idp[q * 4 + 1];
        int i2 = idp[q * 4 + 2], i3 = idp[q * 4 + 3];
        float keep0 = 0.f, keep1 = 0.f;
        #pragma unroll
        for (int tt = 0; tt < 8; ++tt) {
            int cb = tt * 16 + r16;
            float v0 = acc[tt].x + bf2f(xpb[(size_t)i0 * 128 + cb]);
            float v1 = acc[tt].y + bf2f(xpb[(size_t)i1 * 128 + cb]);
            float v2 = acc[tt].z + bf2f(xpb[(size_t)i2 * 128 + cb]);
            float v3 = acc[tt].w + bf2f(xpb[(size_t)i3 * 128 + cb]);
            float mx = fmaxf(fmaxf(v0, v1), fmaxf(v2, v3));
            mx = fmaxf(mx, __shfl_xor(mx, 16));
            mx = fmaxf(mx, __shfl_xor(mx, 32));
            if (tt == q)     keep0 = mx;
            if (tt == q + 4) keep1 = mx;
        }
        size_t base = (size_t)n * 128;
        float x0 = bf2f(xpb[base + l]), x1 = bf2f(xpb[base + l + 64]);
        feat[base + l]      += (keep0 + b3b0 - x0) * lg0 + lb0;
        feat[base + l + 64] += (keep1 + b3b1 - x1) * lg1 + lb1;
    }
}

// ---------------------------------------------------------------------------
extern "C" void kernel_launch(void* const* d_in, const int* in_sizes, int n_in,
                              void* d_out, int out_size, void* d_ws, size_t ws_size,
                              hipStream_t stream) {
    const float* x       = (const float*)d_in[0];
    const float* xyz     = (const float*)d_in[1];
    const float* g_pos   = (const float*)d_in[2];
    const float* ne_w1   = (const float*)d_in[3];
    const float* ne_g1   = (const float*)d_in[4];
    const float* ne_b1   = (const float*)d_in[5];
    const float* ne_w2   = (const float*)d_in[6];
    const float* ne_g2   = (const float*)d_in[7];
    const float* ne_b2   = (const float*)d_in[8];
    const float* ne_w3   = (const float*)d_in[9];
    const float* nbr_g   = (const float*)d_in[10];
    const float* nbr_b   = (const float*)d_in[11];
    const float* gpe_w   = (const float*)d_in[12];
    const float* bm_w1   = (const float*)d_in[13];
    const float* bm_b1   = (const float*)d_in[14];
    const float* bm_w2   = (const float*)d_in[15];
    const float* bm_g    = (const float*)d_in[16];
    const float* bm_b    = (const float*)d_in[17];
    const float* lfa_proj = (const float*)d_in[18];
    const float* lfa_g   = (const float*)d_in[19];
    const float* lfa_b   = (const float*)d_in[20];
    const float* nca_w1  = (const float*)d_in[21];
    const float* nca_b1  = (const float*)d_in[22];
    const float* nca_w2  = (const float*)d_in[23];
    const float* nca_b2  = (const float*)d_in[24];
    const float* nca_w3a = (const float*)d_in[25];
    const float* nca_b3a = (const float*)d_in[26];
    const float* nca_w3b = (const float*)d_in[27];
    const float* nca_b3b = (const float*)d_in[28];
    const float* m_w1    = (const float*)d_in[29];
    const float* m_b1    = (const float*)d_in[30];
    const float* m_w2    = (const float*)d_in[31];
    const float* m_g     = (const float*)d_in[32];
    const float* m_b     = (const float*)d_in[33];
    const float* pp_g    = (const float*)d_in[34];
    const float* pp_b    = (const float*)d_in[35];
    const float* pp_w    = (const float*)d_in[36];
    const int*   knn     = (const int*)d_in[37];

    float* ws    = (float*)d_ws;
    float* dxyz  = ws;                                   // N*48
    float* feat  = dxyz + (size_t)NPTS * 48;             // N*128
    float* Weff  = feat + (size_t)NPTS * 128;            // 1536
    float* cbias = Weff + 1536;                          // 512
    unsigned short* xpb    = (unsigned short*)(cbias + 512);    // N*128
    unsigned short* P_bm1  = xpb + (size_t)NPTS * 128;   // 32768
    unsigned short* P_bm2  = P_bm1 + 32768;              // 32768
    unsigned short* P_m1   = P_bm2 + 32768;              // 65536
    unsigned short* P_m2   = P_m1 + 65536;               // 65536
    unsigned short* P_proj = P_m2 + 65536;               // 65536
    unsigned short* P_pp   = P_proj + 65536;             // 32768
    unsigned short* P_w3a  = P_pp + 32768;               // 32768
    unsigned short* P_w3b  = P_w3a + 32768;              // 65536
    unsigned short* P_ne3  = P_w3b + 65536;              // 4096
    unsigned short* P_gpe  = P_ne3 + 4096;               // 8192
    unsigned short* P_ne1  = P_gpe + 8192;               // 512
    unsigned short* P_ne2  = P_ne1 + 512;                // 1024
    float* out = (float*)d_out;

    hipLaunchKernelGGL(precompute_kernel, dim3(4), dim3(128), 0, stream,
                       nca_w1, nca_b1, nca_w2, nca_b2, nca_w3a, nca_b3a, Weff, cbias);
    hipLaunchKernelGGL(pack_all, dim3(795), dim3(64), 0, stream,
                       bm_w1, bm_w2, m_w1, m_w2, lfa_proj, pp_w, nca_w3a, nca_w3b,
                       ne_w3, gpe_w, ne_w1, ne_g1, ne_w2, ne_g2,
                       P_bm1, P_bm2, P_m1, P_m2, P_proj, P_pp, P_w3a, P_w3b,
                       P_ne3, P_gpe, P_ne1, P_ne2);
    hipLaunchKernelGGL(nbr_embed_v2, dim3(1024), dim3(256), 0, stream,
                       x, xyz, knn, ne_b1, ne_b2, P_ne1, P_ne2, P_ne3,
                       nbr_g, nbr_b, dxyz, feat);
    // bm MLP with fused gpe add and fused proj_0
    hipLaunchKernelGGL(mlp_mfma, dim3(512), dim3(256), 0, stream,
                       feat, P_bm1, bm_b1, P_bm2, bm_g, bm_b,
                       P_gpe, g_pos, P_proj, xpb,
                       (const float*)nullptr, (const float*)nullptr,
                       (const unsigned short*)nullptr, (float*)nullptr);
    for (int i = 0; i < 4; ++i) {
        hipLaunchKernelGGL(lfa_mfma3, dim3(1024), dim3(256), 0, stream,
                           feat, xpb, dxyz, knn,
                           nca_w1 + (size_t)i * 192, nca_b1 + (size_t)i * 64,
                           P_w3a + (size_t)i * 8192,
                           Weff + (size_t)i * 384, cbias + (size_t)i * 128,
                           P_w3b + (size_t)i * 16384,
                           nca_b3b + (size_t)i * 128,
                           lfa_g + (size_t)i * 128, lfa_b + (size_t)i * 128);
        if (i == 0 || i == 2) {
            hipLaunchKernelGGL(linear_mfma, dim3(512), dim3(256), 0, stream,
                               feat, P_proj + (size_t)(i + 1) * 16384, xpb);
        } else if (i == 1) {
            // interleaved MLP 0 with fused proj_2
            hipLaunchKernelGGL(mlp_mfma, dim3(512), dim3(256), 0, stream,
                               feat, P_m1, m_b1, P_m2, m_g, m_b,
                               (const unsigned short*)nullptr, (const float*)nullptr,
                               P_proj + (size_t)2 * 16384, xpb,
                               (const float*)nullptr, (const float*)nullptr,
                               (const unsigned short*)nullptr, (float*)nullptr);
        } else {
            // final interleaved MLP with fused postproj (BN + 128->256 GEMM)
            hipLaunchKernelGGL(mlp_mfma, dim3(512), dim3(256), 0, stream,
                               feat, P_m1 + 32768, m_b1 + 256,
                               P_m2 + 32768, m_g + 128, m_b + 128,
                               (const unsigned short*)nullptr, (const float*)nullptr,
                               (const unsigned short*)nullptr, xpb,
                               pp_g, pp_b, P_pp, out);
        }
    }
}